// Round 1
// baseline (901.678 us; speedup 1.0000x reference)
//
#include <hip/hip_runtime.h>
#include <math.h>

// Dims (CLEVR-scale, fixed)
#define BB 128
#define NN 36
#define DF 512
#define DE 256
#define DV 512
#define HH 256
#define NCC 28
#define LQ 5
#define NE 1296           // N*N edges per batch
#define SCALE 0.04419417382415922f   // 1/sqrt(512)

#define NODE_BLOCKS 288   // 128*36/16
#define ETILES 10368      // 128 batches * 81 tiles of 16 edges
#define EBLOCKS 256       // 1 per CU, 16 waves each
#define EWAVES 4096       // EBLOCKS * 16

typedef __bf16 bf16_8 __attribute__((ext_vector_type(8)));
typedef float  f32_4  __attribute__((ext_vector_type(4)));

__device__ __forceinline__ float sigmoidf_(float x){ return 1.0f/(1.0f + expf(-x)); }
__device__ __forceinline__ float reluf_(float x){ return x > 0.f ? x : 0.f; }

__device__ __forceinline__ bf16_8 cvt8(f32_4 f0, f32_4 f1){
    bf16_8 v;
    #pragma unroll
    for (int i=0;i<4;i++){ v[i] = (__bf16)f0[i]; v[i+4] = (__bf16)f1[i]; }
    return v;
}
// hi/lo split of 8 fp32 into two bf16_8 (3-term split-bf16 emulation, ~2^-18 rel err)
__device__ __forceinline__ void split8(f32_4 f0, f32_4 f1, bf16_8& h, bf16_8& l){
    #pragma unroll
    for (int i=0;i<4;i++){
        __bf16 hi = (__bf16)f0[i];
        h[i] = hi; l[i] = (__bf16)(f0[i] - (float)hi);
        __bf16 hi2 = (__bf16)f1[i];
        h[i+4] = hi2; l[i+4] = (__bf16)(f1[i] - (float)hi2);
    }
}

// async global->LDS DMA, 16B/lane. LDS dest = lds_base + lane*16 (wave-uniform base).
__device__ __forceinline__ void async_copy16(const float* g, float* lds_base){
    __builtin_amdgcn_global_load_lds(
        (const __attribute__((address_space(1))) void*)g,
        (__attribute__((address_space(3))) void*)lds_base, 16, 0, 0);
}

#define XROW 516   // 512 + 4 dwords pad (516 mod 32 == 4 -> uniform banks on frag reads)

// ---------------------------------------------------------------------------
// K0: setup = pack (blocks 0..355) + prep (blocks 356..483)
// ---------------------------------------------------------------------------
__global__ __launch_bounds__(256) void k_setup(
    const float* __restrict__ W_n1, const float* __restrict__ W_n2,
    const float* __restrict__ W_q,  const float* __restrict__ W_c1,
    const float* __restrict__ W_e1, const float* __restrict__ W_c2,
    const float* __restrict__ word_emb, const int* __restrict__ program_inputs,
    const float* __restrict__ W_e2, const float* __restrict__ b_e2,
    __bf16* __restrict__ Pn1h, __bf16* __restrict__ Pn1l,
    __bf16* __restrict__ Pn2h, __bf16* __restrict__ Pn2l,
    __bf16* __restrict__ Pqh,  __bf16* __restrict__ Pql,
    __bf16* __restrict__ Pc1h, __bf16* __restrict__ Pc1l,
    __bf16* __restrict__ Peh,
    __bf16* __restrict__ Pc2h, __bf16* __restrict__ Pc2l,
    float* __restrict__ qws, float* __restrict__ ve, float* __restrict__ se)
{
    int bid = blockIdx.x;
    if (bid < 356){
        // ---- pack branch ----
        const float* W; __bf16 *Ph, *Pl; int N, base, realN;
        if (bid < 64)       { W=W_n1; Ph=Pn1h; Pl=Pn1l; N=256; base=0;   realN=256; }
        else if (bid < 128) { W=W_n2; Ph=Pn2h; Pl=Pn2l; N=512; base=64;  realN=512; }
        else if (bid < 256) { W=W_q;  Ph=Pqh;  Pl=Pql;  N=512; base=128; realN=512; }
        else if (bid < 320) { W=W_c1; Ph=Pc1h; Pl=Pc1l; N=256; base=256; realN=256; }
        else if (bid < 352) { W=W_e1; Ph=Peh;  Pl=nullptr; N=256; base=320; realN=256; }
        else                { W=W_c2; Ph=Pc2h; Pl=Pc2l; N=32;  base=352; realN=28;  }
        int g = (bid-base)*256 + threadIdx.x;
        int lane = g & 63, slot = g >> 6;
        int NT = N >> 4;
        int nt = slot % NT, kt = slot / NT;
        int krow = kt*32 + (lane>>4)*8, ncol = nt*16 + (lane&15);
        #pragma unroll
        for (int j=0;j<8;j++){
            float w = (ncol < realN) ? W[(size_t)(krow+j)*realN + ncol] : 0.f;
            __bf16 hi = (__bf16)w;
            Ph[(size_t)g*8+j] = hi;
            if (Pl) Pl[(size_t)g*8+j] = (__bf16)(w - (float)hi);
        }
    } else {
        // ---- prep branch ----
        int b = bid - 356, t = threadIdx.x, wv = t>>6, lane = t&63;
        int idx[4];
        #pragma unroll
        for (int k=0;k<4;k++) idx[k] = program_inputs[b*LQ + k];
        #pragma unroll
        for (int k=0;k<4;k++){
            qws[((size_t)(b*4+k))*DV + t]       = word_emb[(size_t)idx[k]*DV + t];
            qws[((size_t)(b*4+k))*DV + t + 256] = word_emb[(size_t)idx[k]*DV + t + 256];
        }
        const float* q2p = word_emb + (size_t)idx[2]*DV + lane*8;
        f32_4 qa = *(const f32_4*)q2p, qb = *(const f32_4*)(q2p+4);
        for (int i=0;i<64;i++){
            int h = wv*64 + i;
            const float* wr = W_e2 + (size_t)h*DV + lane*8;
            f32_4 a = *(const f32_4*)wr, c = *(const f32_4*)(wr+4);
            float p = a[0]*qa[0] + a[1]*qa[1] + a[2]*qa[2] + a[3]*qa[3]
                    + c[0]*qb[0] + c[1]*qb[1] + c[2]*qb[2] + c[3]*qb[3];
            #pragma unroll
            for (int off=32; off; off>>=1) p += __shfl_xor(p, off, 64);
            if (lane==0) ve[b*HH + h] = p;
        }
        float pp = b_e2[t]*word_emb[(size_t)idx[2]*DV + t]
                 + b_e2[t+256]*word_emb[(size_t)idx[2]*DV + t + 256];
        __shared__ float red[4];
        #pragma unroll
        for (int off=32; off; off>>=1) pp += __shfl_down(pp, off, 64);
        if ((t&63)==0) red[t>>6] = pp;
        __syncthreads();
        if (t==0) se[b] = red[0]+red[1]+red[2]+red[3];
    }
}

// ---------------------------------------------------------------------------
// K1a: node MLP, standalone (288 blocks x 256 thr, 3 blocks/CU).
// ---------------------------------------------------------------------------
__device__ __forceinline__ void node_body(
    int nb, char* smem,
    const float* __restrict__ X,
    const __bf16* __restrict__ W1h, const __bf16* __restrict__ W1l,
    const float* __restrict__ b1,
    const __bf16* __restrict__ W2h, const __bf16* __restrict__ W2l,
    const float* __restrict__ b2,
    float* __restrict__ nf)
{
    float* xs  = (float*)smem;                    // 16 x XROW fp32 (33024 B)
    __bf16* hh = (__bf16*)(smem + 33024);         // 8 KB
    __bf16* hl = (__bf16*)(smem + 41216);         // 8 KB
    int r0 = nb*16, t = threadIdx.x, wv = t>>6, lane = t&63;
    int m = lane&15, kc = lane>>4;
    int q = lane>>4, c = lane&15;

    #pragma unroll
    for (int r=0;r<4;r++){
        int row = wv*4 + r;
        const float* src = X + (size_t)(r0+row)*DF + lane*4;
        async_copy16(src,       &xs[row*XROW]);
        async_copy16(src + 256, &xs[row*XROW + 256]);
    }
    __syncthreads();

    f32_4 zero = {0.f,0.f,0.f,0.f};
    f32_4 acc1[4];
    #pragma unroll
    for (int nt=0;nt<4;nt++) acc1[nt] = zero;
    for (int kt=0; kt<16; kt++){
        const float* ap = &xs[m*XROW + kt*32 + kc*8];
        f32_4 f0 = *(const f32_4*)ap;
        f32_4 f1 = *(const f32_4*)(ap+4);
        bf16_8 ah, al;
        split8(f0, f1, ah, al);
        #pragma unroll
        for (int nt=0;nt<4;nt++){
            size_t bo = ((size_t)(kt*16 + wv*4+nt)*64 + lane)*8;
            bf16_8 bh = *(const bf16_8*)(W1h + bo);
            bf16_8 bl = *(const bf16_8*)(W1l + bo);
            acc1[nt] = __builtin_amdgcn_mfma_f32_16x16x32_bf16(ah, bh, acc1[nt], 0,0,0);
            acc1[nt] = __builtin_amdgcn_mfma_f32_16x16x32_bf16(al, bh, acc1[nt], 0,0,0);
            acc1[nt] = __builtin_amdgcn_mfma_f32_16x16x32_bf16(ah, bl, acc1[nt], 0,0,0);
        }
    }
    #pragma unroll
    for (int nt=0;nt<4;nt++){
        int col = wv*64 + nt*16 + c;
        float bias = b1[col];
        int kt2 = col>>5, j2 = col&7;
        int lbase = ((col&31)>>3)*16;
        #pragma unroll
        for (int r=0;r<4;r++){
            int row = q*4 + r;
            float v = reluf_(acc1[nt][r] + bias);
            __bf16 hi = (__bf16)v;
            int off = (kt2*64 + lbase + row)*8 + j2;
            hh[off] = hi;
            hl[off] = (__bf16)(v - (float)hi);
        }
    }
    __syncthreads();

    f32_4 acc2[8];
    #pragma unroll
    for (int nt=0;nt<8;nt++) acc2[nt] = zero;
    for (int kt=0; kt<8; kt++){
        bf16_8 ah = *(const bf16_8*)&hh[(kt*64+lane)*8];
        bf16_8 al = *(const bf16_8*)&hl[(kt*64+lane)*8];
        #pragma unroll
        for (int nt=0;nt<8;nt++){
            size_t bo = ((size_t)(kt*32 + wv*8+nt)*64 + lane)*8;
            bf16_8 bh = *(const bf16_8*)(W2h + bo);
            bf16_8 bl = *(const bf16_8*)(W2l + bo);
            acc2[nt] = __builtin_amdgcn_mfma_f32_16x16x32_bf16(ah, bh, acc2[nt], 0,0,0);
            acc2[nt] = __builtin_amdgcn_mfma_f32_16x16x32_bf16(al, bh, acc2[nt], 0,0,0);
            acc2[nt] = __builtin_amdgcn_mfma_f32_16x16x32_bf16(ah, bl, acc2[nt], 0,0,0);
        }
    }
    #pragma unroll
    for (int nt=0;nt<8;nt++){
        int col = wv*128 + nt*16 + c;
        float bias = b2[col];
        #pragma unroll
        for (int r=0;r<4;r++){
            int row = q*4 + r;
            nf[(size_t)(r0+row)*DV + col] = acc2[nt][r] + bias;
        }
    }
}

__global__ __launch_bounds__(256) void k_node(
    const float* __restrict__ X,
    const __bf16* __restrict__ W1h, const __bf16* __restrict__ W1l,
    const float* __restrict__ b1,
    const __bf16* __restrict__ W2h, const __bf16* __restrict__ W2l,
    const float* __restrict__ b2,
    float* __restrict__ nf)
{
    __shared__ __align__(16) char smem[49408];
    node_body(blockIdx.x, smem, X, W1h, W1l, b1, W2h, W2l, b2, nf);
}

// ---------------------------------------------------------------------------
// K1b: edge pass, persistent BW-streaming form.
// 256 blocks x 1024 thr (16 waves), 1 block/CU. Stage packed W_e1 (128 KiB)
// into LDS ONCE per block; then each wave independently grid-strides over
// 16-edge tiles: A-frags loaded global->reg in MFMA layout (coalesced 128B
// row segments), B-frags from LDS, in-wave shuffle epilogue, no barriers in
// the main loop. HBM-bound by design (E streamed exactly once, 170 MB).
// ---------------------------------------------------------------------------
__global__ __launch_bounds__(1024) void k_edge(
    const float* __restrict__ E, const __bf16* __restrict__ Wp,
    const float* __restrict__ b_e1, const float* __restrict__ ve,
    const float* __restrict__ se, float* __restrict__ weit)
{
    __shared__ __align__(16) __bf16 wlds[DE*HH];   // 131072 B
    int t = threadIdx.x, wv = t>>6, lane = t&63;
    int m = lane&15, kc = lane>>4;

    // stage full packed W_e1: 128 chunks of 1KB; wave wv does chunks wv*8..+8
    #pragma unroll
    for (int i=0;i<8;i++){
        int off = (wv*8 + i) << 10;   // byte offset
        async_copy16((const float*)((const char*)Wp + off) + lane*4,
                     (float*)((char*)wlds + off));
    }
    __syncthreads();

    for (int tile = blockIdx.x*16 + wv; tile < ETILES; tile += EWAVES){
        int b = tile/81, tt = tile - b*81;
        int e0 = tt*16;
        // A-frag base: row (edge) = lane&15, k-offset = (lane>>4)*8, per kt +32 floats
        const float* Ea = E + ((size_t)b*NE + e0 + m)*DE + kc*8;

        f32_4 zero = {0.f,0.f,0.f,0.f};
        f32_4 acc[16];
        #pragma unroll
        for (int nt=0;nt<16;nt++) acc[nt] = zero;

        f32_4 c0 = *(const f32_4*)Ea;
        f32_4 c1 = *(const f32_4*)(Ea+4);
        #pragma unroll
        for (int kt=0;kt<8;kt++){
            f32_4 n0, n1;
            if (kt < 7){
                n0 = *(const f32_4*)(Ea + (kt+1)*32);
                n1 = *(const f32_4*)(Ea + (kt+1)*32 + 4);
            }
            bf16_8 af = cvt8(c0, c1);
            #pragma unroll
            for (int nt=0;nt<16;nt++){
                bf16_8 bfrag = *(const bf16_8*)&wlds[((size_t)(kt*16+nt)*64 + lane)*8];
                acc[nt] = __builtin_amdgcn_mfma_f32_16x16x32_bf16(af, bfrag, acc[nt], 0,0,0);
            }
            c0 = n0; c1 = n1;
        }

        // epilogue: per lane col h = nt*16 + m, row (edge) = kc*4 + r
        float s0=0.f, s1=0.f, s2=0.f, s3=0.f;
        #pragma unroll
        for (int nt=0;nt<16;nt++){
            float bev = b_e1[nt*16 + m];
            float vev = ve[b*HH + nt*16 + m];
            s0 = fmaf(reluf_(acc[nt][0] + bev), vev, s0);
            s1 = fmaf(reluf_(acc[nt][1] + bev), vev, s1);
            s2 = fmaf(reluf_(acc[nt][2] + bev), vev, s2);
            s3 = fmaf(reluf_(acc[nt][3] + bev), vev, s3);
        }
        #pragma unroll
        for (int off=1; off<16; off<<=1){
            s0 += __shfl_xor(s0, off, 64);
            s1 += __shfl_xor(s1, off, 64);
            s2 += __shfl_xor(s2, off, 64);
            s3 += __shfl_xor(s3, off, 64);
        }
        float seb = se[b];
        if (m == 0){
            f32_4 o;
            o[0] = sigmoidf_((s0 + seb)*SCALE);
            o[1] = sigmoidf_((s1 + seb)*SCALE);
            o[2] = sigmoidf_((s2 + seb)*SCALE);
            o[3] = sigmoidf_((s3 + seb)*SCALE);
            *(f32_4*)&weit[(size_t)b*NE + e0 + kc*4] = o;
        }
    }
}

// ---------------------------------------------------------------------------
// K2: per-batch attention chain -> x = (pooled * q0) into xws [B,DV]
// ---------------------------------------------------------------------------
__global__ __launch_bounds__(256) void k_attn(
    const float* __restrict__ nf, const float* __restrict__ qws,
    const float* __restrict__ weit, float* __restrict__ xws)
{
    int b = blockIdx.x, t = threadIdx.x;
    int wv = t>>6, lane = t&63;
    __shared__ float a1[NN], a2[NN], a3[NN];
    __shared__ float denom;
    const float* nfb = nf + (size_t)b*NN*DV;
    const float* q0 = qws + ((size_t)(b*4+0))*DV;
    const float* q1 = qws + ((size_t)(b*4+1))*DV;
    const float* q3 = qws + ((size_t)(b*4+3))*DV;

    #pragma unroll
    for (int i=wv; i<NN; i+=4){
        const float* row = nfb + (size_t)i*DV + lane*8;
        const float* qq  = q3 + lane*8;
        f32_4 x0 = *(const f32_4*)row, x1 = *(const f32_4*)(row+4);
        f32_4 y0 = *(const f32_4*)qq,  y1 = *(const f32_4*)(qq+4);
        float p = x0[0]*y0[0] + x0[1]*y0[1] + x0[2]*y0[2] + x0[3]*y0[3]
                + x1[0]*y1[0] + x1[1]*y1[1] + x1[2]*y1[2] + x1[3]*y1[3];
        #pragma unroll
        for (int off=32; off; off>>=1) p += __shfl_xor(p, off, 64);
        if (lane==0) a1[i] = sigmoidf_(p*SCALE);
    }
    __syncthreads();
    if (t < NN){
        const float* wrow = weit + (size_t)b*NE;
        float s = 0.f;
        #pragma unroll
        for (int i=0;i<NN;i++) s = fmaf(a1[i], wrow[i*NN + t], s);
        a2[t] = fminf(fmaxf(s, 0.f), 1.f);
    }
    __syncthreads();
    #pragma unroll
    for (int i=wv; i<NN; i+=4){
        const float* row = nfb + (size_t)i*DV + lane*8;
        const float* qq  = q1 + lane*8;
        f32_4 x0 = *(const f32_4*)row, x1 = *(const f32_4*)(row+4);
        f32_4 y0 = *(const f32_4*)qq,  y1 = *(const f32_4*)(qq+4);
        float p = x0[0]*y0[0] + x0[1]*y0[1] + x0[2]*y0[2] + x0[3]*y0[3]
                + x1[0]*y1[0] + x1[1]*y1[1] + x1[2]*y1[2] + x1[3]*y1[3];
        #pragma unroll
        for (int off=32; off; off>>=1) p += __shfl_xor(p, off, 64);
        if (lane==0) a3[i] = a2[i]*sigmoidf_(p*SCALE);
    }
    __syncthreads();
    if (t==0){
        float s = 0.f;
        for (int i=0;i<NN;i++) s += a3[i];
        denom = 1.f/(s + 1e-8f);
    }
    __syncthreads();
    float p0=0.f, p1=0.f;
    #pragma unroll
    for (int i=0;i<NN;i++){
        float a = a3[i]*denom;
        p0 = fmaf(a, nfb[(size_t)i*DV + t], p0);
        p1 = fmaf(a, nfb[(size_t)i*DV + t + 256], p1);
    }
    xws[(size_t)b*DV + t]       = p0*q0[t];
    xws[(size_t)b*DV + t + 256] = p1*q0[t+256];
}

// ---------------------------------------------------------------------------
// K3: head chain: out = relu(relu(x@W_q+b_q)@W_c1+b_c1)@W_c2+b_c2
// 8 blocks x 16 rows. x staged via DMA fp32; oh/ol aliased over dead x region.
// ---------------------------------------------------------------------------
__global__ __launch_bounds__(256) void k_head(
    const float* __restrict__ xws,
    const __bf16* __restrict__ Wqh, const __bf16* __restrict__ Wql,
    const float* __restrict__ b_q,
    const __bf16* __restrict__ Wc1h, const __bf16* __restrict__ Wc1l,
    const float* __restrict__ b_c1,
    const __bf16* __restrict__ Pc2h, const __bf16* __restrict__ Pc2l,
    const float* __restrict__ b_c2,
    float* __restrict__ out)
{
    __shared__ __align__(16) char smem[49408];
    float* xs   = (float*)smem;                 // 16 x XROW fp32 (33024 B)
    __bf16* oh  = (__bf16*)smem;                // 16 KB, aliases xs (dead after GEMM1)
    __bf16* ol  = (__bf16*)(smem + 16384);      // 16 KB
    __bf16* hfh = (__bf16*)(smem + 33024);      // 8 KB
    __bf16* hfl = (__bf16*)(smem + 41216);      // 8 KB

    int r0 = blockIdx.x*16, t = threadIdx.x, wv = t>>6, lane = t&63;
    int m = lane&15, kc = lane>>4;
    int q = lane>>4, c = lane&15;
    f32_4 zero = {0.f,0.f,0.f,0.f};

    // stage x[16x512] via DMA (coalesced 1KB half-rows)
    #pragma unroll
    for (int r=0;r<4;r++){
        int row = wv*4 + r;
        const float* src = xws + (size_t)(r0+row)*DV + lane*4;
        async_copy16(src,       &xs[row*XROW]);
        async_copy16(src + 256, &xs[row*XROW + 256]);
    }
    __syncthreads();

    // GEMM1: o[16x512] = relu(x @ W_q + b_q)
    f32_4 acc[8];
    #pragma unroll
    for (int nt=0;nt<8;nt++) acc[nt] = zero;
    for (int kt=0; kt<16; kt++){
        const float* ap = &xs[m*XROW + kt*32 + kc*8];
        f32_4 f0 = *(const f32_4*)ap;
        f32_4 f1 = *(const f32_4*)(ap+4);
        bf16_8 ah, al;
        split8(f0, f1, ah, al);
        #pragma unroll
        for (int nt=0;nt<8;nt++){
            size_t bo = ((size_t)(kt*32 + wv*8+nt)*64 + lane)*8;
            bf16_8 bh = *(const bf16_8*)(Wqh + bo);
            bf16_8 bl = *(const bf16_8*)(Wql + bo);
            acc[nt] = __builtin_amdgcn_mfma_f32_16x16x32_bf16(ah, bh, acc[nt], 0,0,0);
            acc[nt] = __builtin_amdgcn_mfma_f32_16x16x32_bf16(al, bh, acc[nt], 0,0,0);
            acc[nt] = __builtin_amdgcn_mfma_f32_16x16x32_bf16(ah, bl, acc[nt], 0,0,0);
        }
    }
    __syncthreads();   // all xs reads done before oh/ol overwrite (alias)
    #pragma unroll
    for (int nt=0;nt<8;nt++){
        int col = wv*128 + nt*16 + c;
        float bias = b_q[col];
        int kt2 = col>>5, j2 = col&7;
        int lbase = ((col&31)>>3)*16;
        #pragma unroll
        for (int r=0;r<4;r++){
            int row = q*4 + r;
            float v = reluf_(acc[nt][r] + bias);
            __bf16 hi = (__bf16)v;
            int off = (kt2*64 + lbase + row)*8 + j2;
            oh[off] = hi;
            ol[off] = (__bf16)(v - (float)hi);
        }
    }
    __syncthreads();

    // GEMM2: h[16x256] = relu(o @ W_c1 + b_c1)
    f32_4 acc2[4];
    #pragma unroll
    for (int nt=0;nt<4;nt++) acc2[nt] = zero;
    for (int kt=0; kt<16; kt++){
        bf16_8 ah = *(const bf16_8*)&oh[(kt*64+lane)*8];
        bf16_8 al = *(const bf16_8*)&ol[(kt*64+lane)*8];
        #pragma unroll
        for (int nt=0;nt<4;nt++){
            size_t bo = ((size_t)(kt*16 + wv*4+nt)*64 + lane)*8;
            bf16_8 bh = *(const bf16_8*)(Wc1h + bo);
            bf16_8 bl = *(const bf16_8*)(Wc1l + bo);
            acc2[nt] = __builtin_amdgcn_mfma_f32_16x16x32_bf16(ah, bh, acc2[nt], 0,0,0);
            acc2[nt] = __builtin_amdgcn_mfma_f32_16x16x32_bf16(al, bh, acc2[nt], 0,0,0);
            acc2[nt] = __builtin_amdgcn_mfma_f32_16x16x32_bf16(ah, bl, acc2[nt], 0,0,0);
        }
    }
    #pragma unroll
    for (int nt=0;nt<4;nt++){
        int col = wv*64 + nt*16 + c;
        float bias = b_c1[col];
        int kt2 = col>>5, j2 = col&7;
        int lbase = ((col&31)>>3)*16;
        #pragma unroll
        for (int r=0;r<4;r++){
            int row = q*4 + r;
            float v = reluf_(acc2[nt][r] + bias);
            __bf16 hi = (__bf16)v;
            int off = (kt2*64 + lbase + row)*8 + j2;
            hfh[off] = hi;
            hfl[off] = (__bf16)(v - (float)hi);
        }
    }
    __syncthreads();

    // GEMM3: out[16x28] = h @ W_c2 + b_c2 via MFMA (N padded to 32)
    if (wv < 2){
        f32_4 acc3 = zero;
        for (int kt=0; kt<8; kt++){
            bf16_8 ah = *(const bf16_8*)&hfh[(kt*64+lane)*8];
            bf16_8 al = *(const bf16_8*)&hfl[(kt*64+lane)*8];
            size_t bo = ((size_t)(kt*2 + wv)*64 + lane)*8;
            bf16_8 bh = *(const bf16_8*)(Pc2h + bo);
            bf16_8 bl = *(const bf16_8*)(Pc2l + bo);
            acc3 = __builtin_amdgcn_mfma_f32_16x16x32_bf16(ah, bh, acc3, 0,0,0);
            acc3 = __builtin_amdgcn_mfma_f32_16x16x32_bf16(al, bh, acc3, 0,0,0);
            acc3 = __builtin_amdgcn_mfma_f32_16x16x32_bf16(ah, bl, acc3, 0,0,0);
        }
        int col = wv*16 + c;
        if (col < NCC){
            float bias = b_c2[col];
            #pragma unroll
            for (int r=0;r<4;r++){
                int row = q*4 + r;
                out[(size_t)(r0+row)*NCC + col] = acc3[r] + bias;
            }
        }
    }
}

// ---------------------------------------------------------------------------
extern "C" void kernel_launch(void* const* d_in, const int* in_sizes, int n_in,
                              void* d_out, int out_size, void* d_ws, size_t ws_size,
                              hipStream_t stream)
{
    const float* node_feats = (const float*)d_in[0];
    const float* edge_feats = (const float*)d_in[1];
    const float* W_n1 = (const float*)d_in[2];
    const float* b_n1 = (const float*)d_in[3];
    const float* W_n2 = (const float*)d_in[4];
    const float* b_n2 = (const float*)d_in[5];
    const float* W_e1 = (const float*)d_in[6];
    const float* b_e1 = (const float*)d_in[7];
    const float* W_e2 = (const float*)d_in[8];
    const float* b_e2 = (const float*)d_in[9];
    const float* W_q  = (const float*)d_in[10];
    const float* b_q  = (const float*)d_in[11];
    const float* W_c1 = (const float*)d_in[12];
    const float* b_c1 = (const float*)d_in[13];
    const float* W_c2 = (const float*)d_in[14];
    const float* b_c2 = (const float*)d_in[15];
    const float* word_emb = (const float*)d_in[16];
    const int* program_inputs = (const int*)d_in[18];

    // workspace layout (all chunks 256B-aligned)
    char* ws = (char*)d_ws;
    float* qws  = (float*)ws; ws += (size_t)BB*4*DV*4;        // 1 MB
    float* ve   = (float*)ws; ws += (size_t)BB*HH*4;          // 128 KB
    float* se   = (float*)ws; ws += 512;
    float* xws  = (float*)ws; ws += (size_t)BB*DV*4;          // 256 KB
    __bf16* Pn1h = (__bf16*)ws; ws += (size_t)DF*HH*2;        // 256 KB
    __bf16* Pn1l = (__bf16*)ws; ws += (size_t)DF*HH*2;
    __bf16* Pn2h = (__bf16*)ws; ws += (size_t)HH*DV*2;
    __bf16* Pn2l = (__bf16*)ws; ws += (size_t)HH*DV*2;
    __bf16* Pqh  = (__bf16*)ws; ws += (size_t)DV*DV*2;        // 512 KB
    __bf16* Pql  = (__bf16*)ws; ws += (size_t)DV*DV*2;
    __bf16* Pc1h = (__bf16*)ws; ws += (size_t)DV*HH*2;
    __bf16* Pc1l = (__bf16*)ws; ws += (size_t)DV*HH*2;
    __bf16* Peh  = (__bf16*)ws; ws += (size_t)DE*HH*2;        // 128 KB
    __bf16* Pc2h = (__bf16*)ws; ws += (size_t)HH*32*2;        // 16 KB
    __bf16* Pc2l = (__bf16*)ws; ws += (size_t)HH*32*2;        // 16 KB
    float* nf   = (float*)ws; ws += (size_t)BB*NN*DV*4;       // 9 MB
    float* weit = (float*)ws; ws += (size_t)BB*NE*4;          // 648 KB

    k_setup<<<484, 256, 0, stream>>>(W_n1, W_n2, W_q, W_c1, W_e1, W_c2,
                                     word_emb, program_inputs, W_e2, b_e2,
                                     Pn1h, Pn1l, Pn2h, Pn2l, Pqh, Pql, Pc1h, Pc1l,
                                     Peh, Pc2h, Pc2l, qws, ve, se);
    k_node<<<NODE_BLOCKS, 256, 0, stream>>>(
        node_feats, Pn1h, Pn1l, b_n1, Pn2h, Pn2l, b_n2, nf);
    k_edge<<<EBLOCKS, 1024, 0, stream>>>(
        edge_feats, Peh, b_e1, ve, se, weit);
    k_attn<<<BB, 256, 0, stream>>>(nf, qws, weit, xws);
    k_head<<<BB/16, 256, 0, stream>>>(xws, Pqh, Pql, b_q, Pc1h, Pc1l, b_c1,
                                      Pc2h, Pc2l, b_c2, (float*)d_out);
}

// Round 2
// 758.867 us; speedup vs baseline: 1.1882x; 1.1882x over previous
//
#include <hip/hip_runtime.h>
#include <math.h>

// Dims (CLEVR-scale, fixed)
#define BB 128
#define NN 36
#define DF 512
#define DE 256
#define DV 512
#define HH 256
#define NCC 28
#define LQ 5
#define NE 1296           // N*N edges per batch
#define SCALE 0.04419417382415922f   // 1/sqrt(512)

#define NODE_BLOCKS 288   // 128*36/16
#define ETILES 10368      // 128 batches * 81 tiles of 16 edges
#define EBLOCKS 256       // 1 per CU (128 KiB LDS), 8 waves each
#define EWAVES 2048       // EBLOCKS * 8

typedef __bf16 bf16_8 __attribute__((ext_vector_type(8)));
typedef float  f32_4  __attribute__((ext_vector_type(4)));

__device__ __forceinline__ float sigmoidf_(float x){ return 1.0f/(1.0f + expf(-x)); }
__device__ __forceinline__ float reluf_(float x){ return x > 0.f ? x : 0.f; }

__device__ __forceinline__ bf16_8 cvt8(f32_4 f0, f32_4 f1){
    bf16_8 v;
    #pragma unroll
    for (int i=0;i<4;i++){ v[i] = (__bf16)f0[i]; v[i+4] = (__bf16)f1[i]; }
    return v;
}
// hi/lo split of 8 fp32 into two bf16_8 (3-term split-bf16 emulation, ~2^-18 rel err)
__device__ __forceinline__ void split8(f32_4 f0, f32_4 f1, bf16_8& h, bf16_8& l){
    #pragma unroll
    for (int i=0;i<4;i++){
        __bf16 hi = (__bf16)f0[i];
        h[i] = hi; l[i] = (__bf16)(f0[i] - (float)hi);
        __bf16 hi2 = (__bf16)f1[i];
        h[i+4] = hi2; l[i+4] = (__bf16)(f1[i] - (float)hi2);
    }
}

// async global->LDS DMA, 16B/lane. LDS dest = lds_base + lane*16 (wave-uniform base).
__device__ __forceinline__ void async_copy16(const float* g, float* lds_base){
    __builtin_amdgcn_global_load_lds(
        (const __attribute__((address_space(1))) void*)g,
        (__attribute__((address_space(3))) void*)lds_base, 16, 0, 0);
}

#define XROW 516   // 512 + 4 dwords pad (516 mod 32 == 4 -> uniform banks on frag reads)

// ---------------------------------------------------------------------------
// K0: setup = pack (blocks 0..355) + prep (blocks 356..483)
// ---------------------------------------------------------------------------
__global__ __launch_bounds__(256) void k_setup(
    const float* __restrict__ W_n1, const float* __restrict__ W_n2,
    const float* __restrict__ W_q,  const float* __restrict__ W_c1,
    const float* __restrict__ W_e1, const float* __restrict__ W_c2,
    const float* __restrict__ word_emb, const int* __restrict__ program_inputs,
    const float* __restrict__ W_e2, const float* __restrict__ b_e2,
    __bf16* __restrict__ Pn1h, __bf16* __restrict__ Pn1l,
    __bf16* __restrict__ Pn2h, __bf16* __restrict__ Pn2l,
    __bf16* __restrict__ Pqh,  __bf16* __restrict__ Pql,
    __bf16* __restrict__ Pc1h, __bf16* __restrict__ Pc1l,
    __bf16* __restrict__ Peh,
    __bf16* __restrict__ Pc2h, __bf16* __restrict__ Pc2l,
    float* __restrict__ qws, float* __restrict__ ve, float* __restrict__ se)
{
    int bid = blockIdx.x;
    if (bid < 356){
        // ---- pack branch ----
        const float* W; __bf16 *Ph, *Pl; int N, base, realN;
        if (bid < 64)       { W=W_n1; Ph=Pn1h; Pl=Pn1l; N=256; base=0;   realN=256; }
        else if (bid < 128) { W=W_n2; Ph=Pn2h; Pl=Pn2l; N=512; base=64;  realN=512; }
        else if (bid < 256) { W=W_q;  Ph=Pqh;  Pl=Pql;  N=512; base=128; realN=512; }
        else if (bid < 320) { W=W_c1; Ph=Pc1h; Pl=Pc1l; N=256; base=256; realN=256; }
        else if (bid < 352) { W=W_e1; Ph=Peh;  Pl=nullptr; N=256; base=320; realN=256; }
        else                { W=W_c2; Ph=Pc2h; Pl=Pc2l; N=32;  base=352; realN=28;  }
        int g = (bid-base)*256 + threadIdx.x;
        int lane = g & 63, slot = g >> 6;
        int NT = N >> 4;
        int nt = slot % NT, kt = slot / NT;
        int krow = kt*32 + (lane>>4)*8, ncol = nt*16 + (lane&15);
        #pragma unroll
        for (int j=0;j<8;j++){
            float w = (ncol < realN) ? W[(size_t)(krow+j)*realN + ncol] : 0.f;
            __bf16 hi = (__bf16)w;
            Ph[(size_t)g*8+j] = hi;
            if (Pl) Pl[(size_t)g*8+j] = (__bf16)(w - (float)hi);
        }
    } else {
        // ---- prep branch ----
        int b = bid - 356, t = threadIdx.x, wv = t>>6, lane = t&63;
        int idx[4];
        #pragma unroll
        for (int k=0;k<4;k++) idx[k] = program_inputs[b*LQ + k];
        #pragma unroll
        for (int k=0;k<4;k++){
            qws[((size_t)(b*4+k))*DV + t]       = word_emb[(size_t)idx[k]*DV + t];
            qws[((size_t)(b*4+k))*DV + t + 256] = word_emb[(size_t)idx[k]*DV + t + 256];
        }
        const float* q2p = word_emb + (size_t)idx[2]*DV + lane*8;
        f32_4 qa = *(const f32_4*)q2p, qb = *(const f32_4*)(q2p+4);
        for (int i=0;i<64;i++){
            int h = wv*64 + i;
            const float* wr = W_e2 + (size_t)h*DV + lane*8;
            f32_4 a = *(const f32_4*)wr, c = *(const f32_4*)(wr+4);
            float p = a[0]*qa[0] + a[1]*qa[1] + a[2]*qa[2] + a[3]*qa[3]
                    + c[0]*qb[0] + c[1]*qb[1] + c[2]*qb[2] + c[3]*qb[3];
            #pragma unroll
            for (int off=32; off; off>>=1) p += __shfl_xor(p, off, 64);
            if (lane==0) ve[b*HH + h] = p;
        }
        float pp = b_e2[t]*word_emb[(size_t)idx[2]*DV + t]
                 + b_e2[t+256]*word_emb[(size_t)idx[2]*DV + t + 256];
        __shared__ float red[4];
        #pragma unroll
        for (int off=32; off; off>>=1) pp += __shfl_down(pp, off, 64);
        if ((t&63)==0) red[t>>6] = pp;
        __syncthreads();
        if (t==0) se[b] = red[0]+red[1]+red[2]+red[3];
    }
}

// ---------------------------------------------------------------------------
// K1a: node MLP, standalone (288 blocks x 256 thr, 3 blocks/CU).
// ---------------------------------------------------------------------------
__device__ __forceinline__ void node_body(
    int nb, char* smem,
    const float* __restrict__ X,
    const __bf16* __restrict__ W1h, const __bf16* __restrict__ W1l,
    const float* __restrict__ b1,
    const __bf16* __restrict__ W2h, const __bf16* __restrict__ W2l,
    const float* __restrict__ b2,
    float* __restrict__ nf)
{
    float* xs  = (float*)smem;                    // 16 x XROW fp32 (33024 B)
    __bf16* hh = (__bf16*)(smem + 33024);         // 8 KB
    __bf16* hl = (__bf16*)(smem + 41216);         // 8 KB
    int r0 = nb*16, t = threadIdx.x, wv = t>>6, lane = t&63;
    int m = lane&15, kc = lane>>4;
    int q = lane>>4, c = lane&15;

    #pragma unroll
    for (int r=0;r<4;r++){
        int row = wv*4 + r;
        const float* src = X + (size_t)(r0+row)*DF + lane*4;
        async_copy16(src,       &xs[row*XROW]);
        async_copy16(src + 256, &xs[row*XROW + 256]);
    }
    __syncthreads();

    f32_4 zero = {0.f,0.f,0.f,0.f};
    f32_4 acc1[4];
    #pragma unroll
    for (int nt=0;nt<4;nt++) acc1[nt] = zero;
    for (int kt=0; kt<16; kt++){
        const float* ap = &xs[m*XROW + kt*32 + kc*8];
        f32_4 f0 = *(const f32_4*)ap;
        f32_4 f1 = *(const f32_4*)(ap+4);
        bf16_8 ah, al;
        split8(f0, f1, ah, al);
        #pragma unroll
        for (int nt=0;nt<4;nt++){
            size_t bo = ((size_t)(kt*16 + wv*4+nt)*64 + lane)*8;
            bf16_8 bh = *(const bf16_8*)(W1h + bo);
            bf16_8 bl = *(const bf16_8*)(W1l + bo);
            acc1[nt] = __builtin_amdgcn_mfma_f32_16x16x32_bf16(ah, bh, acc1[nt], 0,0,0);
            acc1[nt] = __builtin_amdgcn_mfma_f32_16x16x32_bf16(al, bh, acc1[nt], 0,0,0);
            acc1[nt] = __builtin_amdgcn_mfma_f32_16x16x32_bf16(ah, bl, acc1[nt], 0,0,0);
        }
    }
    #pragma unroll
    for (int nt=0;nt<4;nt++){
        int col = wv*64 + nt*16 + c;
        float bias = b1[col];
        int kt2 = col>>5, j2 = col&7;
        int lbase = ((col&31)>>3)*16;
        #pragma unroll
        for (int r=0;r<4;r++){
            int row = q*4 + r;
            float v = reluf_(acc1[nt][r] + bias);
            __bf16 hi = (__bf16)v;
            int off = (kt2*64 + lbase + row)*8 + j2;
            hh[off] = hi;
            hl[off] = (__bf16)(v - (float)hi);
        }
    }
    __syncthreads();

    f32_4 acc2[8];
    #pragma unroll
    for (int nt=0;nt<8;nt++) acc2[nt] = zero;
    for (int kt=0; kt<8; kt++){
        bf16_8 ah = *(const bf16_8*)&hh[(kt*64+lane)*8];
        bf16_8 al = *(const bf16_8*)&hl[(kt*64+lane)*8];
        #pragma unroll
        for (int nt=0;nt<8;nt++){
            size_t bo = ((size_t)(kt*32 + wv*8+nt)*64 + lane)*8;
            bf16_8 bh = *(const bf16_8*)(W2h + bo);
            bf16_8 bl = *(const bf16_8*)(W2l + bo);
            acc2[nt] = __builtin_amdgcn_mfma_f32_16x16x32_bf16(ah, bh, acc2[nt], 0,0,0);
            acc2[nt] = __builtin_amdgcn_mfma_f32_16x16x32_bf16(al, bh, acc2[nt], 0,0,0);
            acc2[nt] = __builtin_amdgcn_mfma_f32_16x16x32_bf16(ah, bl, acc2[nt], 0,0,0);
        }
    }
    #pragma unroll
    for (int nt=0;nt<8;nt++){
        int col = wv*128 + nt*16 + c;
        float bias = b2[col];
        #pragma unroll
        for (int r=0;r<4;r++){
            int row = q*4 + r;
            nf[(size_t)(r0+row)*DV + col] = acc2[nt][r] + bias;
        }
    }
}

__global__ __launch_bounds__(256) void k_node(
    const float* __restrict__ X,
    const __bf16* __restrict__ W1h, const __bf16* __restrict__ W1l,
    const float* __restrict__ b1,
    const __bf16* __restrict__ W2h, const __bf16* __restrict__ W2l,
    const float* __restrict__ b2,
    float* __restrict__ nf)
{
    __shared__ __align__(16) char smem[49408];
    node_body(blockIdx.x, smem, X, W1h, W1l, b1, W2h, W2l, b2, nf);
}

// ---------------------------------------------------------------------------
// K1b: edge pass, persistent BW-streaming form.
// 256 blocks x 512 thr (8 waves), 1 block/CU (128 KiB LDS for packed W_e1).
// __launch_bounds__(512,2) -> VGPR cap 256: acc[16] + depth-2 prefetch live in
// registers (round-1 failed here: 1024 thr capped VGPR at 64 -> acc spilled to
// scratch -> 534 MB of scratch writes). Each wave independently grid-strides
// over 16-edge tiles: A-frags global->reg in MFMA layout (coalesced), B-frags
// from LDS, in-wave shuffle epilogue, no barriers in the main loop.
// ---------------------------------------------------------------------------
__global__ __launch_bounds__(512, 2) void k_edge(
    const float* __restrict__ E, const __bf16* __restrict__ Wp,
    const float* __restrict__ b_e1, const float* __restrict__ ve,
    const float* __restrict__ se, float* __restrict__ weit)
{
    __shared__ __align__(16) __bf16 wlds[DE*HH];   // 131072 B
    int t = threadIdx.x, wv = t>>6, lane = t&63;
    int m = lane&15, kc = lane>>4;

    // stage full packed W_e1: 128 chunks of 1KB; wave wv does chunks wv*16..+16
    #pragma unroll
    for (int i=0;i<16;i++){
        int off = (wv*16 + i) << 10;   // byte offset
        async_copy16((const float*)((const char*)Wp + off) + lane*4,
                     (float*)((char*)wlds + off));
    }
    __syncthreads();

    for (int tile = blockIdx.x*8 + wv; tile < ETILES; tile += EWAVES){
        int b = tile/81, tt = tile - b*81;
        int e0 = tt*16;
        // A-frag base: row (edge) = lane&15, k-offset = (lane>>4)*8, per kt +32 floats
        const float* Ea = E + ((size_t)b*NE + e0 + m)*DE + kc*8;

        f32_4 zero = {0.f,0.f,0.f,0.f};
        f32_4 acc[16];
        #pragma unroll
        for (int nt=0;nt<16;nt++) acc[nt] = zero;

        // depth-2 software pipeline on the A stream (keeps ~4KB/wave in flight)
        f32_4 c0 = *(const f32_4*)(Ea);
        f32_4 c1 = *(const f32_4*)(Ea + 4);
        f32_4 d0 = *(const f32_4*)(Ea + 32);
        f32_4 d1 = *(const f32_4*)(Ea + 36);
        #pragma unroll
        for (int kt=0;kt<8;kt++){
            f32_4 n0, n1;
            if (kt < 6){
                n0 = *(const f32_4*)(Ea + (kt+2)*32);
                n1 = *(const f32_4*)(Ea + (kt+2)*32 + 4);
            }
            bf16_8 af = cvt8(c0, c1);
            #pragma unroll
            for (int nt=0;nt<16;nt++){
                bf16_8 bfrag = *(const bf16_8*)&wlds[((size_t)(kt*16+nt)*64 + lane)*8];
                acc[nt] = __builtin_amdgcn_mfma_f32_16x16x32_bf16(af, bfrag, acc[nt], 0,0,0);
            }
            c0 = d0; c1 = d1;
            d0 = n0; d1 = n1;
        }

        // epilogue: per lane col h = nt*16 + m, row (edge) = kc*4 + r
        float s0=0.f, s1=0.f, s2=0.f, s3=0.f;
        #pragma unroll
        for (int nt=0;nt<16;nt++){
            float bev = b_e1[nt*16 + m];
            float vev = ve[b*HH + nt*16 + m];
            s0 = fmaf(reluf_(acc[nt][0] + bev), vev, s0);
            s1 = fmaf(reluf_(acc[nt][1] + bev), vev, s1);
            s2 = fmaf(reluf_(acc[nt][2] + bev), vev, s2);
            s3 = fmaf(reluf_(acc[nt][3] + bev), vev, s3);
        }
        #pragma unroll
        for (int off=1; off<16; off<<=1){
            s0 += __shfl_xor(s0, off, 64);
            s1 += __shfl_xor(s1, off, 64);
            s2 += __shfl_xor(s2, off, 64);
            s3 += __shfl_xor(s3, off, 64);
        }
        float seb = se[b];
        if (m == 0){
            f32_4 o;
            o[0] = sigmoidf_((s0 + seb)*SCALE);
            o[1] = sigmoidf_((s1 + seb)*SCALE);
            o[2] = sigmoidf_((s2 + seb)*SCALE);
            o[3] = sigmoidf_((s3 + seb)*SCALE);
            *(f32_4*)&weit[(size_t)b*NE + e0 + kc*4] = o;
        }
    }
}

// ---------------------------------------------------------------------------
// K2: per-batch attention chain -> x = (pooled * q0) into xws [B,DV]
// ---------------------------------------------------------------------------
__global__ __launch_bounds__(256) void k_attn(
    const float* __restrict__ nf, const float* __restrict__ qws,
    const float* __restrict__ weit, float* __restrict__ xws)
{
    int b = blockIdx.x, t = threadIdx.x;
    int wv = t>>6, lane = t&63;
    __shared__ float a1[NN], a2[NN], a3[NN];
    __shared__ float denom;
    const float* nfb = nf + (size_t)b*NN*DV;
    const float* q0 = qws + ((size_t)(b*4+0))*DV;
    const float* q1 = qws + ((size_t)(b*4+1))*DV;
    const float* q3 = qws + ((size_t)(b*4+3))*DV;

    #pragma unroll
    for (int i=wv; i<NN; i+=4){
        const float* row = nfb + (size_t)i*DV + lane*8;
        const float* qq  = q3 + lane*8;
        f32_4 x0 = *(const f32_4*)row, x1 = *(const f32_4*)(row+4);
        f32_4 y0 = *(const f32_4*)qq,  y1 = *(const f32_4*)(qq+4);
        float p = x0[0]*y0[0] + x0[1]*y0[1] + x0[2]*y0[2] + x0[3]*y0[3]
                + x1[0]*y1[0] + x1[1]*y1[1] + x1[2]*y1[2] + x1[3]*y1[3];
        #pragma unroll
        for (int off=32; off; off>>=1) p += __shfl_xor(p, off, 64);
        if (lane==0) a1[i] = sigmoidf_(p*SCALE);
    }
    __syncthreads();
    if (t < NN){
        const float* wrow = weit + (size_t)b*NE;
        float s = 0.f;
        #pragma unroll
        for (int i=0;i<NN;i++) s = fmaf(a1[i], wrow[i*NN + t], s);
        a2[t] = fminf(fmaxf(s, 0.f), 1.f);
    }
    __syncthreads();
    #pragma unroll
    for (int i=wv; i<NN; i+=4){
        const float* row = nfb + (size_t)i*DV + lane*8;
        const float* qq  = q1 + lane*8;
        f32_4 x0 = *(const f32_4*)row, x1 = *(const f32_4*)(row+4);
        f32_4 y0 = *(const f32_4*)qq,  y1 = *(const f32_4*)(qq+4);
        float p = x0[0]*y0[0] + x0[1]*y0[1] + x0[2]*y0[2] + x0[3]*y0[3]
                + x1[0]*y1[0] + x1[1]*y1[1] + x1[2]*y1[2] + x1[3]*y1[3];
        #pragma unroll
        for (int off=32; off; off>>=1) p += __shfl_xor(p, off, 64);
        if (lane==0) a3[i] = a2[i]*sigmoidf_(p*SCALE);
    }
    __syncthreads();
    if (t==0){
        float s = 0.f;
        for (int i=0;i<NN;i++) s += a3[i];
        denom = 1.f/(s + 1e-8f);
    }
    __syncthreads();
    float p0=0.f, p1=0.f;
    #pragma unroll
    for (int i=0;i<NN;i++){
        float a = a3[i]*denom;
        p0 = fmaf(a, nfb[(size_t)i*DV + t], p0);
        p1 = fmaf(a, nfb[(size_t)i*DV + t + 256], p1);
    }
    xws[(size_t)b*DV + t]       = p0*q0[t];
    xws[(size_t)b*DV + t + 256] = p1*q0[t+256];
}

// ---------------------------------------------------------------------------
// K3: head chain: out = relu(relu(x@W_q+b_q)@W_c1+b_c1)@W_c2+b_c2
// 8 blocks x 16 rows. x staged via DMA fp32; oh/ol aliased over dead x region.
// ---------------------------------------------------------------------------
__global__ __launch_bounds__(256) void k_head(
    const float* __restrict__ xws,
    const __bf16* __restrict__ Wqh, const __bf16* __restrict__ Wql,
    const float* __restrict__ b_q,
    const __bf16* __restrict__ Wc1h, const __bf16* __restrict__ Wc1l,
    const float* __restrict__ b_c1,
    const __bf16* __restrict__ Pc2h, const __bf16* __restrict__ Pc2l,
    const float* __restrict__ b_c2,
    float* __restrict__ out)
{
    __shared__ __align__(16) char smem[49408];
    float* xs   = (float*)smem;                 // 16 x XROW fp32 (33024 B)
    __bf16* oh  = (__bf16*)smem;                // 16 KB, aliases xs (dead after GEMM1)
    __bf16* ol  = (__bf16*)(smem + 16384);      // 16 KB
    __bf16* hfh = (__bf16*)(smem + 33024);      // 8 KB
    __bf16* hfl = (__bf16*)(smem + 41216);      // 8 KB

    int r0 = blockIdx.x*16, t = threadIdx.x, wv = t>>6, lane = t&63;
    int m = lane&15, kc = lane>>4;
    int q = lane>>4, c = lane&15;
    f32_4 zero = {0.f,0.f,0.f,0.f};

    // stage x[16x512] via DMA (coalesced 1KB half-rows)
    #pragma unroll
    for (int r=0;r<4;r++){
        int row = wv*4 + r;
        const float* src = xws + (size_t)(r0+row)*DV + lane*4;
        async_copy16(src,       &xs[row*XROW]);
        async_copy16(src + 256, &xs[row*XROW + 256]);
    }
    __syncthreads();

    // GEMM1: o[16x512] = relu(x @ W_q + b_q)
    f32_4 acc[8];
    #pragma unroll
    for (int nt=0;nt<8;nt++) acc[nt] = zero;
    for (int kt=0; kt<16; kt++){
        const float* ap = &xs[m*XROW + kt*32 + kc*8];
        f32_4 f0 = *(const f32_4*)ap;
        f32_4 f1 = *(const f32_4*)(ap+4);
        bf16_8 ah, al;
        split8(f0, f1, ah, al);
        #pragma unroll
        for (int nt=0;nt<8;nt++){
            size_t bo = ((size_t)(kt*32 + wv*8+nt)*64 + lane)*8;
            bf16_8 bh = *(const bf16_8*)(Wqh + bo);
            bf16_8 bl = *(const bf16_8*)(Wql + bo);
            acc[nt] = __builtin_amdgcn_mfma_f32_16x16x32_bf16(ah, bh, acc[nt], 0,0,0);
            acc[nt] = __builtin_amdgcn_mfma_f32_16x16x32_bf16(al, bh, acc[nt], 0,0,0);
            acc[nt] = __builtin_amdgcn_mfma_f32_16x16x32_bf16(ah, bl, acc[nt], 0,0,0);
        }
    }
    __syncthreads();   // all xs reads done before oh/ol overwrite (alias)
    #pragma unroll
    for (int nt=0;nt<8;nt++){
        int col = wv*128 + nt*16 + c;
        float bias = b_q[col];
        int kt2 = col>>5, j2 = col&7;
        int lbase = ((col&31)>>3)*16;
        #pragma unroll
        for (int r=0;r<4;r++){
            int row = q*4 + r;
            float v = reluf_(acc[nt][r] + bias);
            __bf16 hi = (__bf16)v;
            int off = (kt2*64 + lbase + row)*8 + j2;
            oh[off] = hi;
            ol[off] = (__bf16)(v - (float)hi);
        }
    }
    __syncthreads();

    // GEMM2: h[16x256] = relu(o @ W_c1 + b_c1)
    f32_4 acc2[4];
    #pragma unroll
    for (int nt=0;nt<4;nt++) acc2[nt] = zero;
    for (int kt=0; kt<16; kt++){
        bf16_8 ah = *(const bf16_8*)&oh[(kt*64+lane)*8];
        bf16_8 al = *(const bf16_8*)&ol[(kt*64+lane)*8];
        #pragma unroll
        for (int nt=0;nt<4;nt++){
            size_t bo = ((size_t)(kt*16 + wv*4+nt)*64 + lane)*8;
            bf16_8 bh = *(const bf16_8*)(Wc1h + bo);
            bf16_8 bl = *(const bf16_8*)(Wc1l + bo);
            acc2[nt] = __builtin_amdgcn_mfma_f32_16x16x32_bf16(ah, bh, acc2[nt], 0,0,0);
            acc2[nt] = __builtin_amdgcn_mfma_f32_16x16x32_bf16(al, bh, acc2[nt], 0,0,0);
            acc2[nt] = __builtin_amdgcn_mfma_f32_16x16x32_bf16(ah, bl, acc2[nt], 0,0,0);
        }
    }
    #pragma unroll
    for (int nt=0;nt<4;nt++){
        int col = wv*64 + nt*16 + c;
        float bias = b_c1[col];
        int kt2 = col>>5, j2 = col&7;
        int lbase = ((col&31)>>3)*16;
        #pragma unroll
        for (int r=0;r<4;r++){
            int row = q*4 + r;
            float v = reluf_(acc2[nt][r] + bias);
            __bf16 hi = (__bf16)v;
            int off = (kt2*64 + lbase + row)*8 + j2;
            hfh[off] = hi;
            hfl[off] = (__bf16)(v - (float)hi);
        }
    }
    __syncthreads();

    // GEMM3: out[16x28] = h @ W_c2 + b_c2 via MFMA (N padded to 32)
    if (wv < 2){
        f32_4 acc3 = zero;
        for (int kt=0; kt<8; kt++){
            bf16_8 ah = *(const bf16_8*)&hfh[(kt*64+lane)*8];
            bf16_8 al = *(const bf16_8*)&hfl[(kt*64+lane)*8];
            size_t bo = ((size_t)(kt*2 + wv)*64 + lane)*8;
            bf16_8 bh = *(const bf16_8*)(Pc2h + bo);
            bf16_8 bl = *(const bf16_8*)(Pc2l + bo);
            acc3 = __builtin_amdgcn_mfma_f32_16x16x32_bf16(ah, bh, acc3, 0,0,0);
            acc3 = __builtin_amdgcn_mfma_f32_16x16x32_bf16(al, bh, acc3, 0,0,0);
            acc3 = __builtin_amdgcn_mfma_f32_16x16x32_bf16(ah, bl, acc3, 0,0,0);
        }
        int col = wv*16 + c;
        if (col < NCC){
            float bias = b_c2[col];
            #pragma unroll
            for (int r=0;r<4;r++){
                int row = q*4 + r;
                out[(size_t)(r0+row)*NCC + col] = acc3[r] + bias;
            }
        }
    }
}

// ---------------------------------------------------------------------------
extern "C" void kernel_launch(void* const* d_in, const int* in_sizes, int n_in,
                              void* d_out, int out_size, void* d_ws, size_t ws_size,
                              hipStream_t stream)
{
    const float* node_feats = (const float*)d_in[0];
    const float* edge_feats = (const float*)d_in[1];
    const float* W_n1 = (const float*)d_in[2];
    const float* b_n1 = (const float*)d_in[3];
    const float* W_n2 = (const float*)d_in[4];
    const float* b_n2 = (const float*)d_in[5];
    const float* W_e1 = (const float*)d_in[6];
    const float* b_e1 = (const float*)d_in[7];
    const float* W_e2 = (const float*)d_in[8];
    const float* b_e2 = (const float*)d_in[9];
    const float* W_q  = (const float*)d_in[10];
    const float* b_q  = (const float*)d_in[11];
    const float* W_c1 = (const float*)d_in[12];
    const float* b_c1 = (const float*)d_in[13];
    const float* W_c2 = (const float*)d_in[14];
    const float* b_c2 = (const float*)d_in[15];
    const float* word_emb = (const float*)d_in[16];
    const int* program_inputs = (const int*)d_in[18];

    // workspace layout (all chunks 256B-aligned)
    char* ws = (char*)d_ws;
    float* qws  = (float*)ws; ws += (size_t)BB*4*DV*4;        // 1 MB
    float* ve   = (float*)ws; ws += (size_t)BB*HH*4;          // 128 KB
    float* se   = (float*)ws; ws += 512;
    float* xws  = (float*)ws; ws += (size_t)BB*DV*4;          // 256 KB
    __bf16* Pn1h = (__bf16*)ws; ws += (size_t)DF*HH*2;        // 256 KB
    __bf16* Pn1l = (__bf16*)ws; ws += (size_t)DF*HH*2;
    __bf16* Pn2h = (__bf16*)ws; ws += (size_t)HH*DV*2;
    __bf16* Pn2l = (__bf16*)ws; ws += (size_t)HH*DV*2;
    __bf16* Pqh  = (__bf16*)ws; ws += (size_t)DV*DV*2;        // 512 KB
    __bf16* Pql  = (__bf16*)ws; ws += (size_t)DV*DV*2;
    __bf16* Pc1h = (__bf16*)ws; ws += (size_t)DV*HH*2;
    __bf16* Pc1l = (__bf16*)ws; ws += (size_t)DV*HH*2;
    __bf16* Peh  = (__bf16*)ws; ws += (size_t)DE*HH*2;        // 128 KB
    __bf16* Pc2h = (__bf16*)ws; ws += (size_t)HH*32*2;        // 16 KB
    __bf16* Pc2l = (__bf16*)ws; ws += (size_t)HH*32*2;        // 16 KB
    float* nf   = (float*)ws; ws += (size_t)BB*NN*DV*4;       // 9 MB
    float* weit = (float*)ws; ws += (size_t)BB*NE*4;          // 648 KB

    k_setup<<<484, 256, 0, stream>>>(W_n1, W_n2, W_q, W_c1, W_e1, W_c2,
                                     word_emb, program_inputs, W_e2, b_e2,
                                     Pn1h, Pn1l, Pn2h, Pn2l, Pqh, Pql, Pc1h, Pc1l,
                                     Peh, Pc2h, Pc2l, qws, ve, se);
    k_node<<<NODE_BLOCKS, 256, 0, stream>>>(
        node_feats, Pn1h, Pn1l, b_n1, Pn2h, Pn2l, b_n2, nf);
    k_edge<<<EBLOCKS, 512, 0, stream>>>(
        edge_feats, Peh, b_e1, ve, se, weit);
    k_attn<<<BB, 256, 0, stream>>>(nf, qws, weit, xws);
    k_head<<<BB/16, 256, 0, stream>>>(xws, Pqh, Pql, b_q, Pc1h, Pc1l, b_c1,
                                      Pc2h, Pc2l, b_c2, (float*)d_out);
}

// Round 3
// 744.419 us; speedup vs baseline: 1.2113x; 1.0194x over previous
//
#include <hip/hip_runtime.h>
#include <math.h>

// Dims (CLEVR-scale, fixed)
#define BB 128
#define NN 36
#define DF 512
#define DE 256
#define DV 512
#define HH 256
#define NCC 28
#define LQ 5
#define NE 1296           // N*N edges per batch
#define SCALE 0.04419417382415922f   // 1/sqrt(512)

#define NODE_BLOCKS 288   // 128*36/16
#define ETILES 10368      // 128 batches * 81 tiles of 16 edges
#define EBLOCKS 256       // 1 per CU (128 KiB LDS), 8 waves each
#define EWAVES 2048       // EBLOCKS * 8

typedef __bf16 bf16_8 __attribute__((ext_vector_type(8)));
typedef float  f32_4  __attribute__((ext_vector_type(4)));

__device__ __forceinline__ float sigmoidf_(float x){ return 1.0f/(1.0f + expf(-x)); }
__device__ __forceinline__ float reluf_(float x){ return x > 0.f ? x : 0.f; }

__device__ __forceinline__ bf16_8 cvt8(f32_4 f0, f32_4 f1){
    bf16_8 v;
    #pragma unroll
    for (int i=0;i<4;i++){ v[i] = (__bf16)f0[i]; v[i+4] = (__bf16)f1[i]; }
    return v;
}
// hi/lo split of 8 fp32 into two bf16_8 (3-term split-bf16 emulation, ~2^-18 rel err)
__device__ __forceinline__ void split8(f32_4 f0, f32_4 f1, bf16_8& h, bf16_8& l){
    #pragma unroll
    for (int i=0;i<4;i++){
        __bf16 hi = (__bf16)f0[i];
        h[i] = hi; l[i] = (__bf16)(f0[i] - (float)hi);
        __bf16 hi2 = (__bf16)f1[i];
        h[i+4] = hi2; l[i+4] = (__bf16)(f1[i] - (float)hi2);
    }
}

// async global->LDS DMA, 16B/lane. LDS dest = lds_base + lane*16 (wave-uniform base).
__device__ __forceinline__ void async_copy16(const float* g, float* lds_base){
    __builtin_amdgcn_global_load_lds(
        (const __attribute__((address_space(1))) void*)g,
        (__attribute__((address_space(3))) void*)lds_base, 16, 0, 0);
}

#define XROW 516   // 512 + 4 dwords pad (516 mod 32 == 4 -> uniform banks on frag reads)

// ---------------------------------------------------------------------------
// K0: setup = pack (blocks 0..355) + prep (blocks 356..483)
// ---------------------------------------------------------------------------
__global__ __launch_bounds__(256) void k_setup(
    const float* __restrict__ W_n1, const float* __restrict__ W_n2,
    const float* __restrict__ W_q,  const float* __restrict__ W_c1,
    const float* __restrict__ W_e1, const float* __restrict__ W_c2,
    const float* __restrict__ word_emb, const int* __restrict__ program_inputs,
    const float* __restrict__ W_e2, const float* __restrict__ b_e2,
    __bf16* __restrict__ Pn1h, __bf16* __restrict__ Pn1l,
    __bf16* __restrict__ Pn2h, __bf16* __restrict__ Pn2l,
    __bf16* __restrict__ Pqh,  __bf16* __restrict__ Pql,
    __bf16* __restrict__ Pc1h, __bf16* __restrict__ Pc1l,
    __bf16* __restrict__ Peh,
    __bf16* __restrict__ Pc2h, __bf16* __restrict__ Pc2l,
    float* __restrict__ qws, float* __restrict__ ve, float* __restrict__ se)
{
    int bid = blockIdx.x;
    if (bid < 356){
        // ---- pack branch ----
        const float* W; __bf16 *Ph, *Pl; int N, base, realN;
        if (bid < 64)       { W=W_n1; Ph=Pn1h; Pl=Pn1l; N=256; base=0;   realN=256; }
        else if (bid < 128) { W=W_n2; Ph=Pn2h; Pl=Pn2l; N=512; base=64;  realN=512; }
        else if (bid < 256) { W=W_q;  Ph=Pqh;  Pl=Pql;  N=512; base=128; realN=512; }
        else if (bid < 320) { W=W_c1; Ph=Pc1h; Pl=Pc1l; N=256; base=256; realN=256; }
        else if (bid < 352) { W=W_e1; Ph=Peh;  Pl=nullptr; N=256; base=320; realN=256; }
        else                { W=W_c2; Ph=Pc2h; Pl=Pc2l; N=32;  base=352; realN=28;  }
        int g = (bid-base)*256 + threadIdx.x;
        int lane = g & 63, slot = g >> 6;
        int NT = N >> 4;
        int nt = slot % NT, kt = slot / NT;
        int krow = kt*32 + (lane>>4)*8, ncol = nt*16 + (lane&15);
        #pragma unroll
        for (int j=0;j<8;j++){
            float w = (ncol < realN) ? W[(size_t)(krow+j)*realN + ncol] : 0.f;
            __bf16 hi = (__bf16)w;
            Ph[(size_t)g*8+j] = hi;
            if (Pl) Pl[(size_t)g*8+j] = (__bf16)(w - (float)hi);
        }
    } else {
        // ---- prep branch ----
        int b = bid - 356, t = threadIdx.x, wv = t>>6, lane = t&63;
        int idx[4];
        #pragma unroll
        for (int k=0;k<4;k++) idx[k] = program_inputs[b*LQ + k];
        #pragma unroll
        for (int k=0;k<4;k++){
            qws[((size_t)(b*4+k))*DV + t]       = word_emb[(size_t)idx[k]*DV + t];
            qws[((size_t)(b*4+k))*DV + t + 256] = word_emb[(size_t)idx[k]*DV + t + 256];
        }
        const float* q2p = word_emb + (size_t)idx[2]*DV + lane*8;
        f32_4 qa = *(const f32_4*)q2p, qb = *(const f32_4*)(q2p+4);
        for (int i=0;i<64;i++){
            int h = wv*64 + i;
            const float* wr = W_e2 + (size_t)h*DV + lane*8;
            f32_4 a = *(const f32_4*)wr, c = *(const f32_4*)(wr+4);
            float p = a[0]*qa[0] + a[1]*qa[1] + a[2]*qa[2] + a[3]*qa[3]
                    + c[0]*qb[0] + c[1]*qb[1] + c[2]*qb[2] + c[3]*qb[3];
            #pragma unroll
            for (int off=32; off; off>>=1) p += __shfl_xor(p, off, 64);
            if (lane==0) ve[b*HH + h] = p;
        }
        float pp = b_e2[t]*word_emb[(size_t)idx[2]*DV + t]
                 + b_e2[t+256]*word_emb[(size_t)idx[2]*DV + t + 256];
        __shared__ float red[4];
        #pragma unroll
        for (int off=32; off; off>>=1) pp += __shfl_down(pp, off, 64);
        if ((t&63)==0) red[t>>6] = pp;
        __syncthreads();
        if (t==0) se[b] = red[0]+red[1]+red[2]+red[3];
    }
}

// ---------------------------------------------------------------------------
// K1a: node MLP, standalone (288 blocks x 256 thr, 3 blocks/CU).
// ---------------------------------------------------------------------------
__device__ __forceinline__ void node_body(
    int nb, char* smem,
    const float* __restrict__ X,
    const __bf16* __restrict__ W1h, const __bf16* __restrict__ W1l,
    const float* __restrict__ b1,
    const __bf16* __restrict__ W2h, const __bf16* __restrict__ W2l,
    const float* __restrict__ b2,
    float* __restrict__ nf)
{
    float* xs  = (float*)smem;                    // 16 x XROW fp32 (33024 B)
    __bf16* hh = (__bf16*)(smem + 33024);         // 8 KB
    __bf16* hl = (__bf16*)(smem + 41216);         // 8 KB
    int r0 = nb*16, t = threadIdx.x, wv = t>>6, lane = t&63;
    int m = lane&15, kc = lane>>4;
    int q = lane>>4, c = lane&15;

    #pragma unroll
    for (int r=0;r<4;r++){
        int row = wv*4 + r;
        const float* src = X + (size_t)(r0+row)*DF + lane*4;
        async_copy16(src,       &xs[row*XROW]);
        async_copy16(src + 256, &xs[row*XROW + 256]);
    }
    __syncthreads();

    f32_4 zero = {0.f,0.f,0.f,0.f};
    f32_4 acc1[4];
    #pragma unroll
    for (int nt=0;nt<4;nt++) acc1[nt] = zero;
    for (int kt=0; kt<16; kt++){
        const float* ap = &xs[m*XROW + kt*32 + kc*8];
        f32_4 f0 = *(const f32_4*)ap;
        f32_4 f1 = *(const f32_4*)(ap+4);
        bf16_8 ah, al;
        split8(f0, f1, ah, al);
        #pragma unroll
        for (int nt=0;nt<4;nt++){
            size_t bo = ((size_t)(kt*16 + wv*4+nt)*64 + lane)*8;
            bf16_8 bh = *(const bf16_8*)(W1h + bo);
            bf16_8 bl = *(const bf16_8*)(W1l + bo);
            acc1[nt] = __builtin_amdgcn_mfma_f32_16x16x32_bf16(ah, bh, acc1[nt], 0,0,0);
            acc1[nt] = __builtin_amdgcn_mfma_f32_16x16x32_bf16(al, bh, acc1[nt], 0,0,0);
            acc1[nt] = __builtin_amdgcn_mfma_f32_16x16x32_bf16(ah, bl, acc1[nt], 0,0,0);
        }
    }
    #pragma unroll
    for (int nt=0;nt<4;nt++){
        int col = wv*64 + nt*16 + c;
        float bias = b1[col];
        int kt2 = col>>5, j2 = col&7;
        int lbase = ((col&31)>>3)*16;
        #pragma unroll
        for (int r=0;r<4;r++){
            int row = q*4 + r;
            float v = reluf_(acc1[nt][r] + bias);
            __bf16 hi = (__bf16)v;
            int off = (kt2*64 + lbase + row)*8 + j2;
            hh[off] = hi;
            hl[off] = (__bf16)(v - (float)hi);
        }
    }
    __syncthreads();

    f32_4 acc2[8];
    #pragma unroll
    for (int nt=0;nt<8;nt++) acc2[nt] = zero;
    for (int kt=0; kt<8; kt++){
        bf16_8 ah = *(const bf16_8*)&hh[(kt*64+lane)*8];
        bf16_8 al = *(const bf16_8*)&hl[(kt*64+lane)*8];
        #pragma unroll
        for (int nt=0;nt<8;nt++){
            size_t bo = ((size_t)(kt*32 + wv*8+nt)*64 + lane)*8;
            bf16_8 bh = *(const bf16_8*)(W2h + bo);
            bf16_8 bl = *(const bf16_8*)(W2l + bo);
            acc2[nt] = __builtin_amdgcn_mfma_f32_16x16x32_bf16(ah, bh, acc2[nt], 0,0,0);
            acc2[nt] = __builtin_amdgcn_mfma_f32_16x16x32_bf16(al, bh, acc2[nt], 0,0,0);
            acc2[nt] = __builtin_amdgcn_mfma_f32_16x16x32_bf16(ah, bl, acc2[nt], 0,0,0);
        }
    }
    #pragma unroll
    for (int nt=0;nt<8;nt++){
        int col = wv*128 + nt*16 + c;
        float bias = b2[col];
        #pragma unroll
        for (int r=0;r<4;r++){
            int row = q*4 + r;
            nf[(size_t)(r0+row)*DV + col] = acc2[nt][r] + bias;
        }
    }
}

__global__ __launch_bounds__(256) void k_node(
    const float* __restrict__ X,
    const __bf16* __restrict__ W1h, const __bf16* __restrict__ W1l,
    const float* __restrict__ b1,
    const __bf16* __restrict__ W2h, const __bf16* __restrict__ W2l,
    const float* __restrict__ b2,
    float* __restrict__ nf)
{
    __shared__ __align__(16) char smem[49408];
    node_body(blockIdx.x, smem, X, W1h, W1l, b1, W2h, W2l, b2, nf);
}

// ---------------------------------------------------------------------------
// K1b: edge pass, persistent BW-streaming form.
// 256 blocks x 512 thr (8 waves), 1 block/CU (128 KiB LDS for packed W_e1).
// __launch_bounds__(512, 1): round-2's (512,2) was interpreted CUDA-style as
// min-2-blocks/CU -> VGPR cap 128 -> acc partially spilled (188 MB scratch
// writes, 387 MB reload fetches). (512,1) caps at >=256 under either
// semantics; kernel needs ~200 live VGPRs -> zero spills expected.
// Each wave independently grid-strides over 16-edge tiles: A-frags
// global->reg in MFMA layout (coalesced), B-frags from LDS, in-wave shuffle
// epilogue, no barriers in the main loop.
// ---------------------------------------------------------------------------
__global__ __launch_bounds__(512, 1) void k_edge(
    const float* __restrict__ E, const __bf16* __restrict__ Wp,
    const float* __restrict__ b_e1, const float* __restrict__ ve,
    const float* __restrict__ se, float* __restrict__ weit)
{
    __shared__ __align__(16) __bf16 wlds[DE*HH];   // 131072 B
    int t = threadIdx.x, wv = t>>6, lane = t&63;
    int m = lane&15, kc = lane>>4;

    // stage full packed W_e1: 128 chunks of 1KB; wave wv does chunks wv*16..+16
    #pragma unroll
    for (int i=0;i<16;i++){
        int off = (wv*16 + i) << 10;   // byte offset
        async_copy16((const float*)((const char*)Wp + off) + lane*4,
                     (float*)((char*)wlds + off));
    }
    __syncthreads();

    for (int tile = blockIdx.x*8 + wv; tile < ETILES; tile += EWAVES){
        int b = tile/81, tt = tile - b*81;
        int e0 = tt*16;
        // A-frag base: row (edge) = lane&15, k-offset = (lane>>4)*8, per kt +32 floats
        const float* Ea = E + ((size_t)b*NE + e0 + m)*DE + kc*8;

        f32_4 zero = {0.f,0.f,0.f,0.f};
        f32_4 acc[16];
        #pragma unroll
        for (int nt=0;nt<16;nt++) acc[nt] = zero;

        // depth-2 software pipeline on the A stream (keeps ~4KB/wave in flight)
        f32_4 c0 = *(const f32_4*)(Ea);
        f32_4 c1 = *(const f32_4*)(Ea + 4);
        f32_4 d0 = *(const f32_4*)(Ea + 32);
        f32_4 d1 = *(const f32_4*)(Ea + 36);
        #pragma unroll
        for (int kt=0;kt<8;kt++){
            f32_4 n0, n1;
            if (kt < 6){
                n0 = *(const f32_4*)(Ea + (kt+2)*32);
                n1 = *(const f32_4*)(Ea + (kt+2)*32 + 4);
            }
            bf16_8 af = cvt8(c0, c1);
            #pragma unroll
            for (int nt=0;nt<16;nt++){
                bf16_8 bfrag = *(const bf16_8*)&wlds[((size_t)(kt*16+nt)*64 + lane)*8];
                acc[nt] = __builtin_amdgcn_mfma_f32_16x16x32_bf16(af, bfrag, acc[nt], 0,0,0);
            }
            c0 = d0; c1 = d1;
            d0 = n0; d1 = n1;
        }

        // epilogue: per lane col h = nt*16 + m, row (edge) = kc*4 + r
        float s0=0.f, s1=0.f, s2=0.f, s3=0.f;
        #pragma unroll
        for (int nt=0;nt<16;nt++){
            float bev = b_e1[nt*16 + m];
            float vev = ve[b*HH + nt*16 + m];
            s0 = fmaf(reluf_(acc[nt][0] + bev), vev, s0);
            s1 = fmaf(reluf_(acc[nt][1] + bev), vev, s1);
            s2 = fmaf(reluf_(acc[nt][2] + bev), vev, s2);
            s3 = fmaf(reluf_(acc[nt][3] + bev), vev, s3);
        }
        #pragma unroll
        for (int off=1; off<16; off<<=1){
            s0 += __shfl_xor(s0, off, 64);
            s1 += __shfl_xor(s1, off, 64);
            s2 += __shfl_xor(s2, off, 64);
            s3 += __shfl_xor(s3, off, 64);
        }
        float seb = se[b];
        if (m == 0){
            f32_4 o;
            o[0] = sigmoidf_((s0 + seb)*SCALE);
            o[1] = sigmoidf_((s1 + seb)*SCALE);
            o[2] = sigmoidf_((s2 + seb)*SCALE);
            o[3] = sigmoidf_((s3 + seb)*SCALE);
            *(f32_4*)&weit[(size_t)b*NE + e0 + kc*4] = o;
        }
    }
}

// ---------------------------------------------------------------------------
// K2: per-batch attention chain -> x = (pooled * q0) into xws [B,DV]
// ---------------------------------------------------------------------------
__global__ __launch_bounds__(256) void k_attn(
    const float* __restrict__ nf, const float* __restrict__ qws,
    const float* __restrict__ weit, float* __restrict__ xws)
{
    int b = blockIdx.x, t = threadIdx.x;
    int wv = t>>6, lane = t&63;
    __shared__ float a1[NN], a2[NN], a3[NN];
    __shared__ float denom;
    const float* nfb = nf + (size_t)b*NN*DV;
    const float* q0 = qws + ((size_t)(b*4+0))*DV;
    const float* q1 = qws + ((size_t)(b*4+1))*DV;
    const float* q3 = qws + ((size_t)(b*4+3))*DV;

    #pragma unroll
    for (int i=wv; i<NN; i+=4){
        const float* row = nfb + (size_t)i*DV + lane*8;
        const float* qq  = q3 + lane*8;
        f32_4 x0 = *(const f32_4*)row, x1 = *(const f32_4*)(row+4);
        f32_4 y0 = *(const f32_4*)qq,  y1 = *(const f32_4*)(qq+4);
        float p = x0[0]*y0[0] + x0[1]*y0[1] + x0[2]*y0[2] + x0[3]*y0[3]
                + x1[0]*y1[0] + x1[1]*y1[1] + x1[2]*y1[2] + x1[3]*y1[3];
        #pragma unroll
        for (int off=32; off; off>>=1) p += __shfl_xor(p, off, 64);
        if (lane==0) a1[i] = sigmoidf_(p*SCALE);
    }
    __syncthreads();
    if (t < NN){
        const float* wrow = weit + (size_t)b*NE;
        float s = 0.f;
        #pragma unroll
        for (int i=0;i<NN;i++) s = fmaf(a1[i], wrow[i*NN + t], s);
        a2[t] = fminf(fmaxf(s, 0.f), 1.f);
    }
    __syncthreads();
    #pragma unroll
    for (int i=wv; i<NN; i+=4){
        const float* row = nfb + (size_t)i*DV + lane*8;
        const float* qq  = q1 + lane*8;
        f32_4 x0 = *(const f32_4*)row, x1 = *(const f32_4*)(row+4);
        f32_4 y0 = *(const f32_4*)qq,  y1 = *(const f32_4*)(qq+4);
        float p = x0[0]*y0[0] + x0[1]*y0[1] + x0[2]*y0[2] + x0[3]*y0[3]
                + x1[0]*y1[0] + x1[1]*y1[1] + x1[2]*y1[2] + x1[3]*y1[3];
        #pragma unroll
        for (int off=32; off; off>>=1) p += __shfl_xor(p, off, 64);
        if (lane==0) a3[i] = a2[i]*sigmoidf_(p*SCALE);
    }
    __syncthreads();
    if (t==0){
        float s = 0.f;
        for (int i=0;i<NN;i++) s += a3[i];
        denom = 1.f/(s + 1e-8f);
    }
    __syncthreads();
    float p0=0.f, p1=0.f;
    #pragma unroll
    for (int i=0;i<NN;i++){
        float a = a3[i]*denom;
        p0 = fmaf(a, nfb[(size_t)i*DV + t], p0);
        p1 = fmaf(a, nfb[(size_t)i*DV + t + 256], p1);
    }
    xws[(size_t)b*DV + t]       = p0*q0[t];
    xws[(size_t)b*DV + t + 256] = p1*q0[t+256];
}

// ---------------------------------------------------------------------------
// K3: head chain: out = relu(relu(x@W_q+b_q)@W_c1+b_c1)@W_c2+b_c2
// 8 blocks x 16 rows. x staged via DMA fp32; oh/ol aliased over dead x region.
// ---------------------------------------------------------------------------
__global__ __launch_bounds__(256) void k_head(
    const float* __restrict__ xws,
    const __bf16* __restrict__ Wqh, const __bf16* __restrict__ Wql,
    const float* __restrict__ b_q,
    const __bf16* __restrict__ Wc1h, const __bf16* __restrict__ Wc1l,
    const float* __restrict__ b_c1,
    const __bf16* __restrict__ Pc2h, const __bf16* __restrict__ Pc2l,
    const float* __restrict__ b_c2,
    float* __restrict__ out)
{
    __shared__ __align__(16) char smem[49408];
    float* xs   = (float*)smem;                 // 16 x XROW fp32 (33024 B)
    __bf16* oh  = (__bf16*)smem;                // 16 KB, aliases xs (dead after GEMM1)
    __bf16* ol  = (__bf16*)(smem + 16384);      // 16 KB
    __bf16* hfh = (__bf16*)(smem + 33024);      // 8 KB
    __bf16* hfl = (__bf16*)(smem + 41216);      // 8 KB

    int r0 = blockIdx.x*16, t = threadIdx.x, wv = t>>6, lane = t&63;
    int m = lane&15, kc = lane>>4;
    int q = lane>>4, c = lane&15;
    f32_4 zero = {0.f,0.f,0.f,0.f};

    // stage x[16x512] via DMA (coalesced 1KB half-rows)
    #pragma unroll
    for (int r=0;r<4;r++){
        int row = wv*4 + r;
        const float* src = xws + (size_t)(r0+row)*DV + lane*4;
        async_copy16(src,       &xs[row*XROW]);
        async_copy16(src + 256, &xs[row*XROW + 256]);
    }
    __syncthreads();

    // GEMM1: o[16x512] = relu(x @ W_q + b_q)
    f32_4 acc[8];
    #pragma unroll
    for (int nt=0;nt<8;nt++) acc[nt] = zero;
    for (int kt=0; kt<16; kt++){
        const float* ap = &xs[m*XROW + kt*32 + kc*8];
        f32_4 f0 = *(const f32_4*)ap;
        f32_4 f1 = *(const f32_4*)(ap+4);
        bf16_8 ah, al;
        split8(f0, f1, ah, al);
        #pragma unroll
        for (int nt=0;nt<8;nt++){
            size_t bo = ((size_t)(kt*32 + wv*8+nt)*64 + lane)*8;
            bf16_8 bh = *(const bf16_8*)(Wqh + bo);
            bf16_8 bl = *(const bf16_8*)(Wql + bo);
            acc[nt] = __builtin_amdgcn_mfma_f32_16x16x32_bf16(ah, bh, acc[nt], 0,0,0);
            acc[nt] = __builtin_amdgcn_mfma_f32_16x16x32_bf16(al, bh, acc[nt], 0,0,0);
            acc[nt] = __builtin_amdgcn_mfma_f32_16x16x32_bf16(ah, bl, acc[nt], 0,0,0);
        }
    }
    __syncthreads();   // all xs reads done before oh/ol overwrite (alias)
    #pragma unroll
    for (int nt=0;nt<8;nt++){
        int col = wv*128 + nt*16 + c;
        float bias = b_q[col];
        int kt2 = col>>5, j2 = col&7;
        int lbase = ((col&31)>>3)*16;
        #pragma unroll
        for (int r=0;r<4;r++){
            int row = q*4 + r;
            float v = reluf_(acc[nt][r] + bias);
            __bf16 hi = (__bf16)v;
            int off = (kt2*64 + lbase + row)*8 + j2;
            oh[off] = hi;
            ol[off] = (__bf16)(v - (float)hi);
        }
    }
    __syncthreads();

    // GEMM2: h[16x256] = relu(o @ W_c1 + b_c1)
    f32_4 acc2[4];
    #pragma unroll
    for (int nt=0;nt<4;nt++) acc2[nt] = zero;
    for (int kt=0; kt<16; kt++){
        bf16_8 ah = *(const bf16_8*)&oh[(kt*64+lane)*8];
        bf16_8 al = *(const bf16_8*)&ol[(kt*64+lane)*8];
        #pragma unroll
        for (int nt=0;nt<4;nt++){
            size_t bo = ((size_t)(kt*16 + wv*4+nt)*64 + lane)*8;
            bf16_8 bh = *(const bf16_8*)(Wc1h + bo);
            bf16_8 bl = *(const bf16_8*)(Wc1l + bo);
            acc2[nt] = __builtin_amdgcn_mfma_f32_16x16x32_bf16(ah, bh, acc2[nt], 0,0,0);
            acc2[nt] = __builtin_amdgcn_mfma_f32_16x16x32_bf16(al, bh, acc2[nt], 0,0,0);
            acc2[nt] = __builtin_amdgcn_mfma_f32_16x16x32_bf16(ah, bl, acc2[nt], 0,0,0);
        }
    }
    #pragma unroll
    for (int nt=0;nt<4;nt++){
        int col = wv*64 + nt*16 + c;
        float bias = b_c1[col];
        int kt2 = col>>5, j2 = col&7;
        int lbase = ((col&31)>>3)*16;
        #pragma unroll
        for (int r=0;r<4;r++){
            int row = q*4 + r;
            float v = reluf_(acc2[nt][r] + bias);
            __bf16 hi = (__bf16)v;
            int off = (kt2*64 + lbase + row)*8 + j2;
            hfh[off] = hi;
            hfl[off] = (__bf16)(v - (float)hi);
        }
    }
    __syncthreads();

    // GEMM3: out[16x28] = h @ W_c2 + b_c2 via MFMA (N padded to 32)
    if (wv < 2){
        f32_4 acc3 = zero;
        for (int kt=0; kt<8; kt++){
            bf16_8 ah = *(const bf16_8*)&hfh[(kt*64+lane)*8];
            bf16_8 al = *(const bf16_8*)&hfl[(kt*64+lane)*8];
            size_t bo = ((size_t)(kt*2 + wv)*64 + lane)*8;
            bf16_8 bh = *(const bf16_8*)(Pc2h + bo);
            bf16_8 bl = *(const bf16_8*)(Pc2l + bo);
            acc3 = __builtin_amdgcn_mfma_f32_16x16x32_bf16(ah, bh, acc3, 0,0,0);
            acc3 = __builtin_amdgcn_mfma_f32_16x16x32_bf16(al, bh, acc3, 0,0,0);
            acc3 = __builtin_amdgcn_mfma_f32_16x16x32_bf16(ah, bl, acc3, 0,0,0);
        }
        int col = wv*16 + c;
        if (col < NCC){
            float bias = b_c2[col];
            #pragma unroll
            for (int r=0;r<4;r++){
                int row = q*4 + r;
                out[(size_t)(r0+row)*NCC + col] = acc3[r] + bias;
            }
        }
    }
}

// ---------------------------------------------------------------------------
extern "C" void kernel_launch(void* const* d_in, const int* in_sizes, int n_in,
                              void* d_out, int out_size, void* d_ws, size_t ws_size,
                              hipStream_t stream)
{
    const float* node_feats = (const float*)d_in[0];
    const float* edge_feats = (const float*)d_in[1];
    const float* W_n1 = (const float*)d_in[2];
    const float* b_n1 = (const float*)d_in[3];
    const float* W_n2 = (const float*)d_in[4];
    const float* b_n2 = (const float*)d_in[5];
    const float* W_e1 = (const float*)d_in[6];
    const float* b_e1 = (const float*)d_in[7];
    const float* W_e2 = (const float*)d_in[8];
    const float* b_e2 = (const float*)d_in[9];
    const float* W_q  = (const float*)d_in[10];
    const float* b_q  = (const float*)d_in[11];
    const float* W_c1 = (const float*)d_in[12];
    const float* b_c1 = (const float*)d_in[13];
    const float* W_c2 = (const float*)d_in[14];
    const float* b_c2 = (const float*)d_in[15];
    const float* word_emb = (const float*)d_in[16];
    const int* program_inputs = (const int*)d_in[18];

    // workspace layout (all chunks 256B-aligned)
    char* ws = (char*)d_ws;
    float* qws  = (float*)ws; ws += (size_t)BB*4*DV*4;        // 1 MB
    float* ve   = (float*)ws; ws += (size_t)BB*HH*4;          // 128 KB
    float* se   = (float*)ws; ws += 512;
    float* xws  = (float*)ws; ws += (size_t)BB*DV*4;          // 256 KB
    __bf16* Pn1h = (__bf16*)ws; ws += (size_t)DF*HH*2;        // 256 KB
    __bf16* Pn1l = (__bf16*)ws; ws += (size_t)DF*HH*2;
    __bf16* Pn2h = (__bf16*)ws; ws += (size_t)HH*DV*2;
    __bf16* Pn2l = (__bf16*)ws; ws += (size_t)HH*DV*2;
    __bf16* Pqh  = (__bf16*)ws; ws += (size_t)DV*DV*2;        // 512 KB
    __bf16* Pql  = (__bf16*)ws; ws += (size_t)DV*DV*2;
    __bf16* Pc1h = (__bf16*)ws; ws += (size_t)DV*HH*2;
    __bf16* Pc1l = (__bf16*)ws; ws += (size_t)DV*HH*2;
    __bf16* Peh  = (__bf16*)ws; ws += (size_t)DE*HH*2;        // 128 KB
    __bf16* Pc2h = (__bf16*)ws; ws += (size_t)HH*32*2;        // 16 KB
    __bf16* Pc2l = (__bf16*)ws; ws += (size_t)HH*32*2;        // 16 KB
    float* nf   = (float*)ws; ws += (size_t)BB*NN*DV*4;       // 9 MB
    float* weit = (float*)ws; ws += (size_t)BB*NE*4;          // 648 KB

    k_setup<<<484, 256, 0, stream>>>(W_n1, W_n2, W_q, W_c1, W_e1, W_c2,
                                     word_emb, program_inputs, W_e2, b_e2,
                                     Pn1h, Pn1l, Pn2h, Pn2l, Pqh, Pql, Pc1h, Pc1l,
                                     Peh, Pc2h, Pc2l, qws, ve, se);
    k_node<<<NODE_BLOCKS, 256, 0, stream>>>(
        node_feats, Pn1h, Pn1l, b_n1, Pn2h, Pn2l, b_n2, nf);
    k_edge<<<EBLOCKS, 512, 0, stream>>>(
        edge_feats, Peh, b_e1, ve, se, weit);
    k_attn<<<BB, 256, 0, stream>>>(nf, qws, weit, xws);
    k_head<<<BB/16, 256, 0, stream>>>(xws, Pqh, Pql, b_q, Pc1h, Pc1l, b_c1,
                                      Pc2h, Pc2l, b_c2, (float*)d_out);
}

// Round 4
// 724.232 us; speedup vs baseline: 1.2450x; 1.0279x over previous
//
#include <hip/hip_runtime.h>
#include <math.h>

// Dims (CLEVR-scale, fixed)
#define BB 128
#define NN 36
#define DF 512
#define DE 256
#define DV 512
#define HH 256
#define NCC 28
#define LQ 5
#define NE 1296           // N*N edges per batch
#define SCALE 0.04419417382415922f   // 1/sqrt(512)

#define NODE_BLOCKS 288   // 128*36/16
#define ETILES 10368      // 128 batches * 81 tiles of 16 edges
#define EBLOCKS 256       // 1 per CU (128 KiB LDS), 8 waves each
#define EWAVES 2048       // EBLOCKS * 8

typedef __bf16 bf16_8 __attribute__((ext_vector_type(8)));
typedef float  f32_4  __attribute__((ext_vector_type(4)));

__device__ __forceinline__ float sigmoidf_(float x){ return 1.0f/(1.0f + expf(-x)); }
__device__ __forceinline__ float reluf_(float x){ return x > 0.f ? x : 0.f; }

__device__ __forceinline__ bf16_8 cvt8(f32_4 f0, f32_4 f1){
    bf16_8 v;
    #pragma unroll
    for (int i=0;i<4;i++){ v[i] = (__bf16)f0[i]; v[i+4] = (__bf16)f1[i]; }
    return v;
}
// hi/lo split of 8 fp32 into two bf16_8 (3-term split-bf16 emulation, ~2^-18 rel err)
__device__ __forceinline__ void split8(f32_4 f0, f32_4 f1, bf16_8& h, bf16_8& l){
    #pragma unroll
    for (int i=0;i<4;i++){
        __bf16 hi = (__bf16)f0[i];
        h[i] = hi; l[i] = (__bf16)(f0[i] - (float)hi);
        __bf16 hi2 = (__bf16)f1[i];
        h[i+4] = hi2; l[i+4] = (__bf16)(f1[i] - (float)hi2);
    }
}

// async global->LDS DMA, 16B/lane. LDS dest = lds_base + lane*16 (wave-uniform base).
__device__ __forceinline__ void async_copy16(const float* g, float* lds_base){
    __builtin_amdgcn_global_load_lds(
        (const __attribute__((address_space(1))) void*)g,
        (__attribute__((address_space(3))) void*)lds_base, 16, 0, 0);
}

#define XROW 516   // 512 + 4 dwords pad (516 mod 32 == 4 -> uniform banks on frag reads)

// ---------------------------------------------------------------------------
// K0: setup = pack (blocks 0..355) + prep (blocks 356..483)
// ---------------------------------------------------------------------------
__global__ __launch_bounds__(256) void k_setup(
    const float* __restrict__ W_n1, const float* __restrict__ W_n2,
    const float* __restrict__ W_q,  const float* __restrict__ W_c1,
    const float* __restrict__ W_e1, const float* __restrict__ W_c2,
    const float* __restrict__ word_emb, const int* __restrict__ program_inputs,
    const float* __restrict__ W_e2, const float* __restrict__ b_e2,
    __bf16* __restrict__ Pn1h, __bf16* __restrict__ Pn1l,
    __bf16* __restrict__ Pn2h, __bf16* __restrict__ Pn2l,
    __bf16* __restrict__ Pqh,  __bf16* __restrict__ Pql,
    __bf16* __restrict__ Pc1h, __bf16* __restrict__ Pc1l,
    __bf16* __restrict__ Peh,
    __bf16* __restrict__ Pc2h, __bf16* __restrict__ Pc2l,
    float* __restrict__ qws, float* __restrict__ ve, float* __restrict__ se)
{
    int bid = blockIdx.x;
    if (bid < 356){
        // ---- pack branch ----
        const float* W; __bf16 *Ph, *Pl; int N, base, realN;
        if (bid < 64)       { W=W_n1; Ph=Pn1h; Pl=Pn1l; N=256; base=0;   realN=256; }
        else if (bid < 128) { W=W_n2; Ph=Pn2h; Pl=Pn2l; N=512; base=64;  realN=512; }
        else if (bid < 256) { W=W_q;  Ph=Pqh;  Pl=Pql;  N=512; base=128; realN=512; }
        else if (bid < 320) { W=W_c1; Ph=Pc1h; Pl=Pc1l; N=256; base=256; realN=256; }
        else if (bid < 352) { W=W_e1; Ph=Peh;  Pl=nullptr; N=256; base=320; realN=256; }
        else                { W=W_c2; Ph=Pc2h; Pl=Pc2l; N=32;  base=352; realN=28;  }
        int g = (bid-base)*256 + threadIdx.x;
        int lane = g & 63, slot = g >> 6;
        int NT = N >> 4;
        int nt = slot % NT, kt = slot / NT;
        int krow = kt*32 + (lane>>4)*8, ncol = nt*16 + (lane&15);
        #pragma unroll
        for (int j=0;j<8;j++){
            float w = (ncol < realN) ? W[(size_t)(krow+j)*realN + ncol] : 0.f;
            __bf16 hi = (__bf16)w;
            Ph[(size_t)g*8+j] = hi;
            if (Pl) Pl[(size_t)g*8+j] = (__bf16)(w - (float)hi);
        }
    } else {
        // ---- prep branch ----
        int b = bid - 356, t = threadIdx.x, wv = t>>6, lane = t&63;
        int idx[4];
        #pragma unroll
        for (int k=0;k<4;k++) idx[k] = program_inputs[b*LQ + k];
        #pragma unroll
        for (int k=0;k<4;k++){
            qws[((size_t)(b*4+k))*DV + t]       = word_emb[(size_t)idx[k]*DV + t];
            qws[((size_t)(b*4+k))*DV + t + 256] = word_emb[(size_t)idx[k]*DV + t + 256];
        }
        const float* q2p = word_emb + (size_t)idx[2]*DV + lane*8;
        f32_4 qa = *(const f32_4*)q2p, qb = *(const f32_4*)(q2p+4);
        for (int i=0;i<64;i++){
            int h = wv*64 + i;
            const float* wr = W_e2 + (size_t)h*DV + lane*8;
            f32_4 a = *(const f32_4*)wr, c = *(const f32_4*)(wr+4);
            float p = a[0]*qa[0] + a[1]*qa[1] + a[2]*qa[2] + a[3]*qa[3]
                    + c[0]*qb[0] + c[1]*qb[1] + c[2]*qb[2] + c[3]*qb[3];
            #pragma unroll
            for (int off=32; off; off>>=1) p += __shfl_xor(p, off, 64);
            if (lane==0) ve[b*HH + h] = p;
        }
        float pp = b_e2[t]*word_emb[(size_t)idx[2]*DV + t]
                 + b_e2[t+256]*word_emb[(size_t)idx[2]*DV + t + 256];
        __shared__ float red[4];
        #pragma unroll
        for (int off=32; off; off>>=1) pp += __shfl_down(pp, off, 64);
        if ((t&63)==0) red[t>>6] = pp;
        __syncthreads();
        if (t==0) se[b] = red[0]+red[1]+red[2]+red[3];
    }
}

// ---------------------------------------------------------------------------
// K1a: node MLP, standalone (288 blocks x 256 thr, 3 blocks/CU).
// ---------------------------------------------------------------------------
__device__ __forceinline__ void node_body(
    int nb, char* smem,
    const float* __restrict__ X,
    const __bf16* __restrict__ W1h, const __bf16* __restrict__ W1l,
    const float* __restrict__ b1,
    const __bf16* __restrict__ W2h, const __bf16* __restrict__ W2l,
    const float* __restrict__ b2,
    float* __restrict__ nf)
{
    float* xs  = (float*)smem;                    // 16 x XROW fp32 (33024 B)
    __bf16* hh = (__bf16*)(smem + 33024);         // 8 KB
    __bf16* hl = (__bf16*)(smem + 41216);         // 8 KB
    int r0 = nb*16, t = threadIdx.x, wv = t>>6, lane = t&63;
    int m = lane&15, kc = lane>>4;
    int q = lane>>4, c = lane&15;

    #pragma unroll
    for (int r=0;r<4;r++){
        int row = wv*4 + r;
        const float* src = X + (size_t)(r0+row)*DF + lane*4;
        async_copy16(src,       &xs[row*XROW]);
        async_copy16(src + 256, &xs[row*XROW + 256]);
    }
    __syncthreads();

    f32_4 zero = {0.f,0.f,0.f,0.f};
    f32_4 acc1[4];
    #pragma unroll
    for (int nt=0;nt<4;nt++) acc1[nt] = zero;
    for (int kt=0; kt<16; kt++){
        const float* ap = &xs[m*XROW + kt*32 + kc*8];
        f32_4 f0 = *(const f32_4*)ap;
        f32_4 f1 = *(const f32_4*)(ap+4);
        bf16_8 ah, al;
        split8(f0, f1, ah, al);
        #pragma unroll
        for (int nt=0;nt<4;nt++){
            size_t bo = ((size_t)(kt*16 + wv*4+nt)*64 + lane)*8;
            bf16_8 bh = *(const bf16_8*)(W1h + bo);
            bf16_8 bl = *(const bf16_8*)(W1l + bo);
            acc1[nt] = __builtin_amdgcn_mfma_f32_16x16x32_bf16(ah, bh, acc1[nt], 0,0,0);
            acc1[nt] = __builtin_amdgcn_mfma_f32_16x16x32_bf16(al, bh, acc1[nt], 0,0,0);
            acc1[nt] = __builtin_amdgcn_mfma_f32_16x16x32_bf16(ah, bl, acc1[nt], 0,0,0);
        }
    }
    #pragma unroll
    for (int nt=0;nt<4;nt++){
        int col = wv*64 + nt*16 + c;
        float bias = b1[col];
        int kt2 = col>>5, j2 = col&7;
        int lbase = ((col&31)>>3)*16;
        #pragma unroll
        for (int r=0;r<4;r++){
            int row = q*4 + r;
            float v = reluf_(acc1[nt][r] + bias);
            __bf16 hi = (__bf16)v;
            int off = (kt2*64 + lbase + row)*8 + j2;
            hh[off] = hi;
            hl[off] = (__bf16)(v - (float)hi);
        }
    }
    __syncthreads();

    f32_4 acc2[8];
    #pragma unroll
    for (int nt=0;nt<8;nt++) acc2[nt] = zero;
    for (int kt=0; kt<8; kt++){
        bf16_8 ah = *(const bf16_8*)&hh[(kt*64+lane)*8];
        bf16_8 al = *(const bf16_8*)&hl[(kt*64+lane)*8];
        #pragma unroll
        for (int nt=0;nt<8;nt++){
            size_t bo = ((size_t)(kt*32 + wv*8+nt)*64 + lane)*8;
            bf16_8 bh = *(const bf16_8*)(W2h + bo);
            bf16_8 bl = *(const bf16_8*)(W2l + bo);
            acc2[nt] = __builtin_amdgcn_mfma_f32_16x16x32_bf16(ah, bh, acc2[nt], 0,0,0);
            acc2[nt] = __builtin_amdgcn_mfma_f32_16x16x32_bf16(al, bh, acc2[nt], 0,0,0);
            acc2[nt] = __builtin_amdgcn_mfma_f32_16x16x32_bf16(ah, bl, acc2[nt], 0,0,0);
        }
    }
    #pragma unroll
    for (int nt=0;nt<8;nt++){
        int col = wv*128 + nt*16 + c;
        float bias = b2[col];
        #pragma unroll
        for (int r=0;r<4;r++){
            int row = q*4 + r;
            nf[(size_t)(r0+row)*DV + col] = acc2[nt][r] + bias;
        }
    }
}

__global__ __launch_bounds__(256) void k_node(
    const float* __restrict__ X,
    const __bf16* __restrict__ W1h, const __bf16* __restrict__ W1l,
    const float* __restrict__ b1,
    const __bf16* __restrict__ W2h, const __bf16* __restrict__ W2l,
    const float* __restrict__ b2,
    float* __restrict__ nf)
{
    __shared__ __align__(16) char smem[49408];
    node_body(blockIdx.x, smem, X, W1h, W1l, b1, W2h, W2l, b2, nf);
}

// ---------------------------------------------------------------------------
// K1b: edge pass, persistent BW-streaming form.
// 256 blocks x 512 thr (8 waves), 1 block/CU (128 KiB LDS for packed W_e1).
// Round 2/3 showed the allocator pins this kernel at 128 VGPRs regardless of
// launch-bounds, and acc[16] (64 VGPRs) + hoisted fp32 A-pipeline spilled
// (188 MB scratch writes / ~390 MB reload fetches = the whole 367 us).
// Restructure to fit under 128: (a) cache A as bf16 a[8] (32 VGPRs) via the
// depth-2 fp32 pipeline, E still read once; (b) split H into two 128-col
// halves with acc[8] (32 VGPRs), partial relu*ve reduction after each half.
// Peak live ~110 VGPRs -> no spills. No barriers in the main loop.
// ---------------------------------------------------------------------------
__global__ __launch_bounds__(512, 1) void k_edge(
    const float* __restrict__ E, const __bf16* __restrict__ Wp,
    const float* __restrict__ b_e1, const float* __restrict__ ve,
    const float* __restrict__ se, float* __restrict__ weit)
{
    __shared__ __align__(16) __bf16 wlds[DE*HH];   // 131072 B
    int t = threadIdx.x, wv = t>>6, lane = t&63;
    int m = lane&15, kc = lane>>4;

    // stage full packed W_e1: 128 chunks of 1KB; wave wv does chunks wv*16..+16
    #pragma unroll
    for (int i=0;i<16;i++){
        int off = (wv*16 + i) << 10;   // byte offset
        async_copy16((const float*)((const char*)Wp + off) + lane*4,
                     (float*)((char*)wlds + off));
    }
    __syncthreads();

    for (int tile = blockIdx.x*8 + wv; tile < ETILES; tile += EWAVES){
        int b = tile/81, tt = tile - b*81;
        int e0 = tt*16;
        // A-frag base: row (edge) = lane&15, k-offset = (lane>>4)*8, per kt +32 floats
        const float* Ea = E + ((size_t)b*NE + e0 + m)*DE + kc*8;

        // load all 8 A-frags, converting to bf16 as they arrive (depth-2 fp32
        // pipeline keeps transient fp32 pressure low; a[] is 32 VGPRs).
        bf16_8 a[8];
        f32_4 c0 = *(const f32_4*)(Ea);
        f32_4 c1 = *(const f32_4*)(Ea + 4);
        f32_4 d0 = *(const f32_4*)(Ea + 32);
        f32_4 d1 = *(const f32_4*)(Ea + 36);
        #pragma unroll
        for (int kt=0;kt<8;kt++){
            f32_4 n0, n1;
            if (kt < 6){
                n0 = *(const f32_4*)(Ea + (kt+2)*32);
                n1 = *(const f32_4*)(Ea + (kt+2)*32 + 4);
            }
            a[kt] = cvt8(c0, c1);
            c0 = d0; c1 = d1;
            d0 = n0; d1 = n1;
        }

        f32_4 zero = {0.f,0.f,0.f,0.f};
        float s0=0.f, s1=0.f, s2=0.f, s3=0.f;
        float seb = se[b];
        const float* veb = ve + b*HH;

        // ---- half 0: output cols h = 0..127 ----
        {
            f32_4 acc[8];
            #pragma unroll
            for (int nt=0;nt<8;nt++) acc[nt] = zero;
            #pragma unroll
            for (int kt=0;kt<8;kt++){
                #pragma unroll
                for (int nt=0;nt<8;nt++){
                    bf16_8 bfrag = *(const bf16_8*)&wlds[((size_t)(kt*16+nt)*64 + lane)*8];
                    acc[nt] = __builtin_amdgcn_mfma_f32_16x16x32_bf16(a[kt], bfrag, acc[nt], 0,0,0);
                }
            }
            #pragma unroll
            for (int nt=0;nt<8;nt++){
                float bev = b_e1[nt*16 + m];
                float vev = veb[nt*16 + m];
                s0 = fmaf(reluf_(acc[nt][0] + bev), vev, s0);
                s1 = fmaf(reluf_(acc[nt][1] + bev), vev, s1);
                s2 = fmaf(reluf_(acc[nt][2] + bev), vev, s2);
                s3 = fmaf(reluf_(acc[nt][3] + bev), vev, s3);
            }
        }
        // ---- half 1: output cols h = 128..255 ----
        {
            f32_4 acc[8];
            #pragma unroll
            for (int nt=0;nt<8;nt++) acc[nt] = zero;
            #pragma unroll
            for (int kt=0;kt<8;kt++){
                #pragma unroll
                for (int nt=0;nt<8;nt++){
                    bf16_8 bfrag = *(const bf16_8*)&wlds[((size_t)(kt*16+nt+8)*64 + lane)*8];
                    acc[nt] = __builtin_amdgcn_mfma_f32_16x16x32_bf16(a[kt], bfrag, acc[nt], 0,0,0);
                }
            }
            #pragma unroll
            for (int nt=0;nt<8;nt++){
                float bev = b_e1[(nt+8)*16 + m];
                float vev = veb[(nt+8)*16 + m];
                s0 = fmaf(reluf_(acc[nt][0] + bev), vev, s0);
                s1 = fmaf(reluf_(acc[nt][1] + bev), vev, s1);
                s2 = fmaf(reluf_(acc[nt][2] + bev), vev, s2);
                s3 = fmaf(reluf_(acc[nt][3] + bev), vev, s3);
            }
        }

        #pragma unroll
        for (int off=1; off<16; off<<=1){
            s0 += __shfl_xor(s0, off, 64);
            s1 += __shfl_xor(s1, off, 64);
            s2 += __shfl_xor(s2, off, 64);
            s3 += __shfl_xor(s3, off, 64);
        }
        if (m == 0){
            f32_4 o;
            o[0] = sigmoidf_((s0 + seb)*SCALE);
            o[1] = sigmoidf_((s1 + seb)*SCALE);
            o[2] = sigmoidf_((s2 + seb)*SCALE);
            o[3] = sigmoidf_((s3 + seb)*SCALE);
            *(f32_4*)&weit[(size_t)b*NE + e0 + kc*4] = o;
        }
    }
}

// ---------------------------------------------------------------------------
// K2: per-batch attention chain -> x = (pooled * q0) into xws [B,DV]
// ---------------------------------------------------------------------------
__global__ __launch_bounds__(256) void k_attn(
    const float* __restrict__ nf, const float* __restrict__ qws,
    const float* __restrict__ weit, float* __restrict__ xws)
{
    int b = blockIdx.x, t = threadIdx.x;
    int wv = t>>6, lane = t&63;
    __shared__ float a1[NN], a2[NN], a3[NN];
    __shared__ float denom;
    const float* nfb = nf + (size_t)b*NN*DV;
    const float* q0 = qws + ((size_t)(b*4+0))*DV;
    const float* q1 = qws + ((size_t)(b*4+1))*DV;
    const float* q3 = qws + ((size_t)(b*4+3))*DV;

    #pragma unroll
    for (int i=wv; i<NN; i+=4){
        const float* row = nfb + (size_t)i*DV + lane*8;
        const float* qq  = q3 + lane*8;
        f32_4 x0 = *(const f32_4*)row, x1 = *(const f32_4*)(row+4);
        f32_4 y0 = *(const f32_4*)qq,  y1 = *(const f32_4*)(qq+4);
        float p = x0[0]*y0[0] + x0[1]*y0[1] + x0[2]*y0[2] + x0[3]*y0[3]
                + x1[0]*y1[0] + x1[1]*y1[1] + x1[2]*y1[2] + x1[3]*y1[3];
        #pragma unroll
        for (int off=32; off; off>>=1) p += __shfl_xor(p, off, 64);
        if (lane==0) a1[i] = sigmoidf_(p*SCALE);
    }
    __syncthreads();
    if (t < NN){
        const float* wrow = weit + (size_t)b*NE;
        float s = 0.f;
        #pragma unroll
        for (int i=0;i<NN;i++) s = fmaf(a1[i], wrow[i*NN + t], s);
        a2[t] = fminf(fmaxf(s, 0.f), 1.f);
    }
    __syncthreads();
    #pragma unroll
    for (int i=wv; i<NN; i+=4){
        const float* row = nfb + (size_t)i*DV + lane*8;
        const float* qq  = q1 + lane*8;
        f32_4 x0 = *(const f32_4*)row, x1 = *(const f32_4*)(row+4);
        f32_4 y0 = *(const f32_4*)qq,  y1 = *(const f32_4*)(qq+4);
        float p = x0[0]*y0[0] + x0[1]*y0[1] + x0[2]*y0[2] + x0[3]*y0[3]
                + x1[0]*y1[0] + x1[1]*y1[1] + x1[2]*y1[2] + x1[3]*y1[3];
        #pragma unroll
        for (int off=32; off; off>>=1) p += __shfl_xor(p, off, 64);
        if (lane==0) a3[i] = a2[i]*sigmoidf_(p*SCALE);
    }
    __syncthreads();
    if (t==0){
        float s = 0.f;
        for (int i=0;i<NN;i++) s += a3[i];
        denom = 1.f/(s + 1e-8f);
    }
    __syncthreads();
    float p0=0.f, p1=0.f;
    #pragma unroll
    for (int i=0;i<NN;i++){
        float a = a3[i]*denom;
        p0 = fmaf(a, nfb[(size_t)i*DV + t], p0);
        p1 = fmaf(a, nfb[(size_t)i*DV + t + 256], p1);
    }
    xws[(size_t)b*DV + t]       = p0*q0[t];
    xws[(size_t)b*DV + t + 256] = p1*q0[t+256];
}

// ---------------------------------------------------------------------------
// K3: head chain: out = relu(relu(x@W_q+b_q)@W_c1+b_c1)@W_c2+b_c2
// 8 blocks x 16 rows. x staged via DMA fp32; oh/ol aliased over dead x region.
// ---------------------------------------------------------------------------
__global__ __launch_bounds__(256) void k_head(
    const float* __restrict__ xws,
    const __bf16* __restrict__ Wqh, const __bf16* __restrict__ Wql,
    const float* __restrict__ b_q,
    const __bf16* __restrict__ Wc1h, const __bf16* __restrict__ Wc1l,
    const float* __restrict__ b_c1,
    const __bf16* __restrict__ Pc2h, const __bf16* __restrict__ Pc2l,
    const float* __restrict__ b_c2,
    float* __restrict__ out)
{
    __shared__ __align__(16) char smem[49408];
    float* xs   = (float*)smem;                 // 16 x XROW fp32 (33024 B)
    __bf16* oh  = (__bf16*)smem;                // 16 KB, aliases xs (dead after GEMM1)
    __bf16* ol  = (__bf16*)(smem + 16384);      // 16 KB
    __bf16* hfh = (__bf16*)(smem + 33024);      // 8 KB
    __bf16* hfl = (__bf16*)(smem + 41216);      // 8 KB

    int r0 = blockIdx.x*16, t = threadIdx.x, wv = t>>6, lane = t&63;
    int m = lane&15, kc = lane>>4;
    int q = lane>>4, c = lane&15;
    f32_4 zero = {0.f,0.f,0.f,0.f};

    // stage x[16x512] via DMA (coalesced 1KB half-rows)
    #pragma unroll
    for (int r=0;r<4;r++){
        int row = wv*4 + r;
        const float* src = xws + (size_t)(r0+row)*DV + lane*4;
        async_copy16(src,       &xs[row*XROW]);
        async_copy16(src + 256, &xs[row*XROW + 256]);
    }
    __syncthreads();

    // GEMM1: o[16x512] = relu(x @ W_q + b_q)
    f32_4 acc[8];
    #pragma unroll
    for (int nt=0;nt<8;nt++) acc[nt] = zero;
    for (int kt=0; kt<16; kt++){
        const float* ap = &xs[m*XROW + kt*32 + kc*8];
        f32_4 f0 = *(const f32_4*)ap;
        f32_4 f1 = *(const f32_4*)(ap+4);
        bf16_8 ah, al;
        split8(f0, f1, ah, al);
        #pragma unroll
        for (int nt=0;nt<8;nt++){
            size_t bo = ((size_t)(kt*32 + wv*8+nt)*64 + lane)*8;
            bf16_8 bh = *(const bf16_8*)(Wqh + bo);
            bf16_8 bl = *(const bf16_8*)(Wql + bo);
            acc[nt] = __builtin_amdgcn_mfma_f32_16x16x32_bf16(ah, bh, acc[nt], 0,0,0);
            acc[nt] = __builtin_amdgcn_mfma_f32_16x16x32_bf16(al, bh, acc[nt], 0,0,0);
            acc[nt] = __builtin_amdgcn_mfma_f32_16x16x32_bf16(ah, bl, acc[nt], 0,0,0);
        }
    }
    __syncthreads();   // all xs reads done before oh/ol overwrite (alias)
    #pragma unroll
    for (int nt=0;nt<8;nt++){
        int col = wv*128 + nt*16 + c;
        float bias = b_q[col];
        int kt2 = col>>5, j2 = col&7;
        int lbase = ((col&31)>>3)*16;
        #pragma unroll
        for (int r=0;r<4;r++){
            int row = q*4 + r;
            float v = reluf_(acc[nt][r] + bias);
            __bf16 hi = (__bf16)v;
            int off = (kt2*64 + lbase + row)*8 + j2;
            oh[off] = hi;
            ol[off] = (__bf16)(v - (float)hi);
        }
    }
    __syncthreads();

    // GEMM2: h[16x256] = relu(o @ W_c1 + b_c1)
    f32_4 acc2[4];
    #pragma unroll
    for (int nt=0;nt<4;nt++) acc2[nt] = zero;
    for (int kt=0; kt<16; kt++){
        bf16_8 ah = *(const bf16_8*)&oh[(kt*64+lane)*8];
        bf16_8 al = *(const bf16_8*)&ol[(kt*64+lane)*8];
        #pragma unroll
        for (int nt=0;nt<4;nt++){
            size_t bo = ((size_t)(kt*16 + wv*4+nt)*64 + lane)*8;
            bf16_8 bh = *(const bf16_8*)(Wc1h + bo);
            bf16_8 bl = *(const bf16_8*)(Wc1l + bo);
            acc2[nt] = __builtin_amdgcn_mfma_f32_16x16x32_bf16(ah, bh, acc2[nt], 0,0,0);
            acc2[nt] = __builtin_amdgcn_mfma_f32_16x16x32_bf16(al, bh, acc2[nt], 0,0,0);
            acc2[nt] = __builtin_amdgcn_mfma_f32_16x16x32_bf16(ah, bl, acc2[nt], 0,0,0);
        }
    }
    #pragma unroll
    for (int nt=0;nt<4;nt++){
        int col = wv*64 + nt*16 + c;
        float bias = b_c1[col];
        int kt2 = col>>5, j2 = col&7;
        int lbase = ((col&31)>>3)*16;
        #pragma unroll
        for (int r=0;r<4;r++){
            int row = q*4 + r;
            float v = reluf_(acc2[nt][r] + bias);
            __bf16 hi = (__bf16)v;
            int off = (kt2*64 + lbase + row)*8 + j2;
            hfh[off] = hi;
            hfl[off] = (__bf16)(v - (float)hi);
        }
    }
    __syncthreads();

    // GEMM3: out[16x28] = h @ W_c2 + b_c2 via MFMA (N padded to 32)
    if (wv < 2){
        f32_4 acc3 = zero;
        for (int kt=0; kt<8; kt++){
            bf16_8 ah = *(const bf16_8*)&hfh[(kt*64+lane)*8];
            bf16_8 al = *(const bf16_8*)&hfl[(kt*64+lane)*8];
            size_t bo = ((size_t)(kt*2 + wv)*64 + lane)*8;
            bf16_8 bh = *(const bf16_8*)(Pc2h + bo);
            bf16_8 bl = *(const bf16_8*)(Pc2l + bo);
            acc3 = __builtin_amdgcn_mfma_f32_16x16x32_bf16(ah, bh, acc3, 0,0,0);
            acc3 = __builtin_amdgcn_mfma_f32_16x16x32_bf16(al, bh, acc3, 0,0,0);
            acc3 = __builtin_amdgcn_mfma_f32_16x16x32_bf16(ah, bl, acc3, 0,0,0);
        }
        int col = wv*16 + c;
        if (col < NCC){
            float bias = b_c2[col];
            #pragma unroll
            for (int r=0;r<4;r++){
                int row = q*4 + r;
                out[(size_t)(r0+row)*NCC + col] = acc3[r] + bias;
            }
        }
    }
}

// ---------------------------------------------------------------------------
extern "C" void kernel_launch(void* const* d_in, const int* in_sizes, int n_in,
                              void* d_out, int out_size, void* d_ws, size_t ws_size,
                              hipStream_t stream)
{
    const float* node_feats = (const float*)d_in[0];
    const float* edge_feats = (const float*)d_in[1];
    const float* W_n1 = (const float*)d_in[2];
    const float* b_n1 = (const float*)d_in[3];
    const float* W_n2 = (const float*)d_in[4];
    const float* b_n2 = (const float*)d_in[5];
    const float* W_e1 = (const float*)d_in[6];
    const float* b_e1 = (const float*)d_in[7];
    const float* W_e2 = (const float*)d_in[8];
    const float* b_e2 = (const float*)d_in[9];
    const float* W_q  = (const float*)d_in[10];
    const float* b_q  = (const float*)d_in[11];
    const float* W_c1 = (const float*)d_in[12];
    const float* b_c1 = (const float*)d_in[13];
    const float* W_c2 = (const float*)d_in[14];
    const float* b_c2 = (const float*)d_in[15];
    const float* word_emb = (const float*)d_in[16];
    const int* program_inputs = (const int*)d_in[18];

    // workspace layout (all chunks 256B-aligned)
    char* ws = (char*)d_ws;
    float* qws  = (float*)ws; ws += (size_t)BB*4*DV*4;        // 1 MB
    float* ve   = (float*)ws; ws += (size_t)BB*HH*4;          // 128 KB
    float* se   = (float*)ws; ws += 512;
    float* xws  = (float*)ws; ws += (size_t)BB*DV*4;          // 256 KB
    __bf16* Pn1h = (__bf16*)ws; ws += (size_t)DF*HH*2;        // 256 KB
    __bf16* Pn1l = (__bf16*)ws; ws += (size_t)DF*HH*2;
    __bf16* Pn2h = (__bf16*)ws; ws += (size_t)HH*DV*2;
    __bf16* Pn2l = (__bf16*)ws; ws += (size_t)HH*DV*2;
    __bf16* Pqh  = (__bf16*)ws; ws += (size_t)DV*DV*2;        // 512 KB
    __bf16* Pql  = (__bf16*)ws; ws += (size_t)DV*DV*2;
    __bf16* Pc1h = (__bf16*)ws; ws += (size_t)DV*HH*2;
    __bf16* Pc1l = (__bf16*)ws; ws += (size_t)DV*HH*2;
    __bf16* Peh  = (__bf16*)ws; ws += (size_t)DE*HH*2;        // 128 KB
    __bf16* Pc2h = (__bf16*)ws; ws += (size_t)HH*32*2;        // 16 KB
    __bf16* Pc2l = (__bf16*)ws; ws += (size_t)HH*32*2;        // 16 KB
    float* nf   = (float*)ws; ws += (size_t)BB*NN*DV*4;       // 9 MB
    float* weit = (float*)ws; ws += (size_t)BB*NE*4;          // 648 KB

    k_setup<<<484, 256, 0, stream>>>(W_n1, W_n2, W_q, W_c1, W_e1, W_c2,
                                     word_emb, program_inputs, W_e2, b_e2,
                                     Pn1h, Pn1l, Pn2h, Pn2l, Pqh, Pql, Pc1h, Pc1l,
                                     Peh, Pc2h, Pc2l, qws, ve, se);
    k_node<<<NODE_BLOCKS, 256, 0, stream>>>(
        node_feats, Pn1h, Pn1l, b_n1, Pn2h, Pn2l, b_n2, nf);
    k_edge<<<EBLOCKS, 512, 0, stream>>>(
        edge_feats, Peh, b_e1, ve, se, weit);
    k_attn<<<BB, 256, 0, stream>>>(nf, qws, weit, xws);
    k_head<<<BB/16, 256, 0, stream>>>(xws, Pqh, Pql, b_q, Pc1h, Pc1l, b_c1,
                                      Pc2h, Pc2l, b_c2, (float*)d_out);
}

// Round 5
// 455.356 us; speedup vs baseline: 1.9802x; 1.5905x over previous
//
#include <hip/hip_runtime.h>
#include <math.h>

// Dims (CLEVR-scale, fixed)
#define BB 128
#define NN 36
#define DF 512
#define DE 256
#define DV 512
#define HH 256
#define NCC 28
#define LQ 5
#define NE 1296           // N*N edges per batch
#define SCALE 0.04419417382415922f   // 1/sqrt(512)

#define ETILES 10368      // 128 batches * 81 tiles of 16 edges
#define EBLOCKS 256       // 1 per CU (128 KiB LDS), 8 waves each
#define EWAVES 2048       // EBLOCKS * 8
#define NODE_PAIRS 144    // 288 node tiles, 2 per 512-thr block

typedef __bf16 bf16_8 __attribute__((ext_vector_type(8)));
typedef float  f32_4  __attribute__((ext_vector_type(4)));

__device__ __forceinline__ float sigmoidf_(float x){ return 1.0f/(1.0f + expf(-x)); }
__device__ __forceinline__ float reluf_(float x){ return x > 0.f ? x : 0.f; }

__device__ __forceinline__ bf16_8 cvt8(f32_4 f0, f32_4 f1){
    bf16_8 v;
    #pragma unroll
    for (int i=0;i<4;i++){ v[i] = (__bf16)f0[i]; v[i+4] = (__bf16)f1[i]; }
    return v;
}
// hi/lo split of 8 fp32 into two bf16_8 (3-term split-bf16 emulation, ~2^-18 rel err)
__device__ __forceinline__ void split8(f32_4 f0, f32_4 f1, bf16_8& h, bf16_8& l){
    #pragma unroll
    for (int i=0;i<4;i++){
        __bf16 hi = (__bf16)f0[i];
        h[i] = hi; l[i] = (__bf16)(f0[i] - (float)hi);
        __bf16 hi2 = (__bf16)f1[i];
        h[i+4] = hi2; l[i+4] = (__bf16)(f1[i] - (float)hi2);
    }
}

// async global->LDS DMA, 16B/lane. LDS dest = lds_base + lane*16 (wave-uniform base).
__device__ __forceinline__ void async_copy16(const float* g, float* lds_base){
    __builtin_amdgcn_global_load_lds(
        (const __attribute__((address_space(1))) void*)g,
        (__attribute__((address_space(3))) void*)lds_base, 16, 0, 0);
}

#define XROW 516   // 512 + 4 dwords pad (516 mod 32 == 4 -> uniform banks on frag reads)

// ---------------------------------------------------------------------------
// K0: setup = pack Pn1/Pn2/Pe (blocks 0..159) + prep (blocks 160..287)
// (W_q/W_c1/W_c2 packs removed: head is now fp32 GEMV in k_attnhead)
// ---------------------------------------------------------------------------
__global__ __launch_bounds__(256) void k_setup(
    const float* __restrict__ W_n1, const float* __restrict__ W_n2,
    const float* __restrict__ W_e1,
    const float* __restrict__ word_emb, const int* __restrict__ program_inputs,
    const float* __restrict__ W_e2, const float* __restrict__ b_e2,
    __bf16* __restrict__ Pn1h, __bf16* __restrict__ Pn1l,
    __bf16* __restrict__ Pn2h, __bf16* __restrict__ Pn2l,
    __bf16* __restrict__ Peh,
    float* __restrict__ qws, float* __restrict__ ve, float* __restrict__ se)
{
    int bid = blockIdx.x;
    if (bid < 160){
        // ---- pack branch ----
        const float* W; __bf16 *Ph, *Pl; int N, base, realN;
        if (bid < 64)       { W=W_n1; Ph=Pn1h; Pl=Pn1l; N=256; base=0;   realN=256; }
        else if (bid < 128) { W=W_n2; Ph=Pn2h; Pl=Pn2l; N=512; base=64;  realN=512; }
        else                { W=W_e1; Ph=Peh;  Pl=nullptr; N=256; base=128; realN=256; }
        int g = (bid-base)*256 + threadIdx.x;
        int lane = g & 63, slot = g >> 6;
        int NT = N >> 4;
        int nt = slot % NT, kt = slot / NT;
        int krow = kt*32 + (lane>>4)*8, ncol = nt*16 + (lane&15);
        #pragma unroll
        for (int j=0;j<8;j++){
            float w = (ncol < realN) ? W[(size_t)(krow+j)*realN + ncol] : 0.f;
            __bf16 hi = (__bf16)w;
            Ph[(size_t)g*8+j] = hi;
            if (Pl) Pl[(size_t)g*8+j] = (__bf16)(w - (float)hi);
        }
    } else {
        // ---- prep branch ----
        int b = bid - 160, t = threadIdx.x, wv = t>>6, lane = t&63;
        int idx[4];
        #pragma unroll
        for (int k=0;k<4;k++) idx[k] = program_inputs[b*LQ + k];
        #pragma unroll
        for (int k=0;k<4;k++){
            qws[((size_t)(b*4+k))*DV + t]       = word_emb[(size_t)idx[k]*DV + t];
            qws[((size_t)(b*4+k))*DV + t + 256] = word_emb[(size_t)idx[k]*DV + t + 256];
        }
        const float* q2p = word_emb + (size_t)idx[2]*DV + lane*8;
        f32_4 qa = *(const f32_4*)q2p, qb = *(const f32_4*)(q2p+4);
        for (int i=0;i<64;i++){
            int h = wv*64 + i;
            const float* wr = W_e2 + (size_t)h*DV + lane*8;
            f32_4 a = *(const f32_4*)wr, c = *(const f32_4*)(wr+4);
            float p = a[0]*qa[0] + a[1]*qa[1] + a[2]*qa[2] + a[3]*qa[3]
                    + c[0]*qb[0] + c[1]*qb[1] + c[2]*qb[2] + c[3]*qb[3];
            #pragma unroll
            for (int off=32; off; off>>=1) p += __shfl_xor(p, off, 64);
            if (lane==0) ve[b*HH + h] = p;
        }
        float pp = b_e2[t]*word_emb[(size_t)idx[2]*DV + t]
                 + b_e2[t+256]*word_emb[(size_t)idx[2]*DV + t + 256];
        __shared__ float red[4];
        #pragma unroll
        for (int off=32; off; off>>=1) pp += __shfl_down(pp, off, 64);
        if ((t&63)==0) red[t>>6] = pp;
        __syncthreads();
        if (t==0) se[b] = red[0]+red[1]+red[2]+red[3];
    }
}

// ---------------------------------------------------------------------------
// node MLP body, parameterized on a 256-thread slice (t256 in 0..255)
// ---------------------------------------------------------------------------
__device__ __forceinline__ void node_body(
    int nb, char* smem, int t,
    const float* __restrict__ X,
    const __bf16* __restrict__ W1h, const __bf16* __restrict__ W1l,
    const float* __restrict__ b1,
    const __bf16* __restrict__ W2h, const __bf16* __restrict__ W2l,
    const float* __restrict__ b2,
    float* __restrict__ nf)
{
    float* xs  = (float*)smem;                    // 16 x XROW fp32 (33024 B)
    __bf16* hh = (__bf16*)(smem + 33024);         // 8 KB
    __bf16* hl = (__bf16*)(smem + 41216);         // 8 KB
    int r0 = nb*16, wv = t>>6, lane = t&63;
    int m = lane&15, kc = lane>>4;
    int q = lane>>4, c = lane&15;

    #pragma unroll
    for (int r=0;r<4;r++){
        int row = wv*4 + r;
        const float* src = X + (size_t)(r0+row)*DF + lane*4;
        async_copy16(src,       &xs[row*XROW]);
        async_copy16(src + 256, &xs[row*XROW + 256]);
    }
    __syncthreads();

    f32_4 zero = {0.f,0.f,0.f,0.f};
    f32_4 acc1[4];
    #pragma unroll
    for (int nt=0;nt<4;nt++) acc1[nt] = zero;
    for (int kt=0; kt<16; kt++){
        const float* ap = &xs[m*XROW + kt*32 + kc*8];
        f32_4 f0 = *(const f32_4*)ap;
        f32_4 f1 = *(const f32_4*)(ap+4);
        bf16_8 ah, al;
        split8(f0, f1, ah, al);
        #pragma unroll
        for (int nt=0;nt<4;nt++){
            size_t bo = ((size_t)(kt*16 + wv*4+nt)*64 + lane)*8;
            bf16_8 bh = *(const bf16_8*)(W1h + bo);
            bf16_8 bl = *(const bf16_8*)(W1l + bo);
            acc1[nt] = __builtin_amdgcn_mfma_f32_16x16x32_bf16(ah, bh, acc1[nt], 0,0,0);
            acc1[nt] = __builtin_amdgcn_mfma_f32_16x16x32_bf16(al, bh, acc1[nt], 0,0,0);
            acc1[nt] = __builtin_amdgcn_mfma_f32_16x16x32_bf16(ah, bl, acc1[nt], 0,0,0);
        }
    }
    #pragma unroll
    for (int nt=0;nt<4;nt++){
        int col = wv*64 + nt*16 + c;
        float bias = b1[col];
        int kt2 = col>>5, j2 = col&7;
        int lbase = ((col&31)>>3)*16;
        #pragma unroll
        for (int r=0;r<4;r++){
            int row = q*4 + r;
            float v = reluf_(acc1[nt][r] + bias);
            __bf16 hi = (__bf16)v;
            int off = (kt2*64 + lbase + row)*8 + j2;
            hh[off] = hi;
            hl[off] = (__bf16)(v - (float)hi);
        }
    }
    __syncthreads();

    f32_4 acc2[8];
    #pragma unroll
    for (int nt=0;nt<8;nt++) acc2[nt] = zero;
    for (int kt=0; kt<8; kt++){
        bf16_8 ah = *(const bf16_8*)&hh[(kt*64+lane)*8];
        bf16_8 al = *(const bf16_8*)&hl[(kt*64+lane)*8];
        #pragma unroll
        for (int nt=0;nt<8;nt++){
            size_t bo = ((size_t)(kt*32 + wv*8+nt)*64 + lane)*8;
            bf16_8 bh = *(const bf16_8*)(W2h + bo);
            bf16_8 bl = *(const bf16_8*)(W2l + bo);
            acc2[nt] = __builtin_amdgcn_mfma_f32_16x16x32_bf16(ah, bh, acc2[nt], 0,0,0);
            acc2[nt] = __builtin_amdgcn_mfma_f32_16x16x32_bf16(al, bh, acc2[nt], 0,0,0);
            acc2[nt] = __builtin_amdgcn_mfma_f32_16x16x32_bf16(ah, bl, acc2[nt], 0,0,0);
        }
    }
    #pragma unroll
    for (int nt=0;nt<8;nt++){
        int col = wv*128 + nt*16 + c;
        float bias = b2[col];
        #pragma unroll
        for (int r=0;r<4;r++){
            int row = q*4 + r;
            nf[(size_t)(r0+row)*DV + col] = acc2[nt][r] + bias;
        }
    }
}

// ---------------------------------------------------------------------------
// edge body: persistent BW-streaming, spill-proofed.
// Rounds 2-4 lesson: with the kt loop fully unrolled, the scheduler hoists
// dozens of ds_reads + epilogue loads past the MFMA block -> >128 live ->
// acc spills to scratch (constant ~190 MB writes across all 3 bodies).
// Fix: #pragma unroll 1 on kt (and half) loops so at most one iteration's
// 8 ds_reads can be hoisted. acc[8] per H-half, JIT depth-1 A-prefetch.
// Peak live ~100 VGPR < 128 cap. E re-read per half mostly L2-hit.
// ---------------------------------------------------------------------------
__device__ __forceinline__ void edge_body(
    char* smem,
    const float* __restrict__ E, const __bf16* __restrict__ Wp,
    const float* __restrict__ b_e1, const float* __restrict__ ve,
    const float* __restrict__ se, float* __restrict__ weit)
{
    __bf16* wlds = (__bf16*)smem;   // 131072 B packed W_e1
    int t = threadIdx.x, wv = t>>6, lane = t&63;
    int m = lane&15, kc = lane>>4;

    // stage full packed W_e1: 128 chunks of 1KB; wave wv does chunks wv*16..+16
    #pragma unroll
    for (int i=0;i<16;i++){
        int off = (wv*16 + i) << 10;   // byte offset
        async_copy16((const float*)((const char*)Wp + off) + lane*4,
                     (float*)((char*)wlds + off));
    }
    __syncthreads();

    for (int tile = blockIdx.x*8 + wv; tile < ETILES; tile += EWAVES){
        int b = tile/81, tt = tile - b*81;
        int e0 = tt*16;
        // A-frag base: row (edge) = lane&15, k-offset = (lane>>4)*8, per kt +32 floats
        const float* Ea = E + ((size_t)b*NE + e0 + m)*DE + kc*8;
        float seb = se[b];
        float s0=0.f, s1=0.f, s2=0.f, s3=0.f;

        #pragma unroll 1
        for (int half=0; half<2; half++){
            f32_4 zero = {0.f,0.f,0.f,0.f};
            f32_4 acc[8];
            #pragma unroll
            for (int nt=0;nt<8;nt++) acc[nt] = zero;

            f32_4 c0 = *(const f32_4*)Ea;
            f32_4 c1 = *(const f32_4*)(Ea + 4);
            #pragma unroll 1
            for (int kt=0;kt<8;kt++){
                int kn = (kt+1)&7;   // branchless prefetch (kt=7 reads kt=0, discarded)
                f32_4 n0 = *(const f32_4*)(Ea + kn*32);
                f32_4 n1 = *(const f32_4*)(Ea + kn*32 + 4);
                bf16_8 af = cvt8(c0, c1);
                const __bf16* wb = wlds + ((size_t)(kt*16 + half*8)*64 + lane)*8;
                #pragma unroll
                for (int nt=0;nt<8;nt++){
                    bf16_8 bfrag = *(const bf16_8*)(wb + (size_t)nt*512);
                    acc[nt] = __builtin_amdgcn_mfma_f32_16x16x32_bf16(af, bfrag, acc[nt], 0,0,0);
                }
                c0 = n0; c1 = n1;
            }
            #pragma unroll
            for (int nt=0;nt<8;nt++){
                int h = (half*8 + nt)*16 + m;
                float bev = b_e1[h];
                float vev = ve[b*HH + h];
                s0 = fmaf(reluf_(acc[nt][0] + bev), vev, s0);
                s1 = fmaf(reluf_(acc[nt][1] + bev), vev, s1);
                s2 = fmaf(reluf_(acc[nt][2] + bev), vev, s2);
                s3 = fmaf(reluf_(acc[nt][3] + bev), vev, s3);
            }
        }

        #pragma unroll
        for (int off=1; off<16; off<<=1){
            s0 += __shfl_xor(s0, off, 64);
            s1 += __shfl_xor(s1, off, 64);
            s2 += __shfl_xor(s2, off, 64);
            s3 += __shfl_xor(s3, off, 64);
        }
        if (m == 0){
            f32_4 o;
            o[0] = sigmoidf_((s0 + seb)*SCALE);
            o[1] = sigmoidf_((s1 + seb)*SCALE);
            o[2] = sigmoidf_((s2 + seb)*SCALE);
            o[3] = sigmoidf_((s3 + seb)*SCALE);
            *(f32_4*)&weit[(size_t)b*NE + e0 + kc*4] = o;
        }
    }
}

// ---------------------------------------------------------------------------
// K1: main = edge (blocks 0..255, persistent) + node (blocks 256..399, two
// 256-thr sub-tiles per block). Outputs independent -> no ordering needed.
// Union LDS: edge 128 KiB, node 2x49408 = 96.5 KiB.
// ---------------------------------------------------------------------------
__global__ __launch_bounds__(512, 1) void k_main(
    const float* __restrict__ E, const __bf16* __restrict__ Wp,
    const float* __restrict__ b_e1, const float* __restrict__ ve,
    const float* __restrict__ se, float* __restrict__ weit,
    const float* __restrict__ X,
    const __bf16* __restrict__ W1h, const __bf16* __restrict__ W1l,
    const float* __restrict__ b1,
    const __bf16* __restrict__ W2h, const __bf16* __restrict__ W2l,
    const float* __restrict__ b2,
    float* __restrict__ nf)
{
    __shared__ __align__(16) char smem[131072];
    int bx = blockIdx.x;
    if (bx < EBLOCKS){
        edge_body(smem, E, Wp, b_e1, ve, se, weit);
    } else {
        int sub = threadIdx.x >> 8;          // 0 or 1
        int nb = (bx - EBLOCKS)*2 + sub;     // node tile 0..287
        node_body(nb, smem + sub*49408, threadIdx.x & 255,
                  X, W1h, W1l, b1, W2h, W2l, b2, nf);
    }
}

// ---------------------------------------------------------------------------
// K2: attention chain + full head, fused per batch (512 thr).
// attn: as before (8-wave striping). head: fp32 GEMVs (x@Wq -> relu -> @Wc1
// -> relu -> @Wc2), thread t owns output col t; W reads coalesced across t,
// weights served from L2 (shared across the 16 blocks per XCD).
// ---------------------------------------------------------------------------
__global__ __launch_bounds__(512) void k_attnhead(
    const float* __restrict__ nf, const float* __restrict__ qws,
    const float* __restrict__ weit,
    const float* __restrict__ Wq,  const float* __restrict__ bq,
    const float* __restrict__ Wc1, const float* __restrict__ bc1,
    const float* __restrict__ Wc2, const float* __restrict__ bc2,
    float* __restrict__ out)
{
    int b = blockIdx.x, t = threadIdx.x;
    int wv = t>>6, lane = t&63;
    __shared__ float a1[NN], a3[NN];
    __shared__ float xsh[DV];    // (pooled * q0)
    __shared__ float osh[DV];    // relu(x@Wq+bq)
    __shared__ float hsh[HH];    // relu(o@Wc1+bc1)
    __shared__ float denom;
    const float* nfb = nf + (size_t)b*NN*DV;
    const float* q0 = qws + ((size_t)(b*4+0))*DV;
    const float* q1 = qws + ((size_t)(b*4+1))*DV;
    const float* q3 = qws + ((size_t)(b*4+3))*DV;

    for (int i=wv; i<NN; i+=8){
        const float* row = nfb + (size_t)i*DV + lane*8;
        const float* qq  = q3 + lane*8;
        f32_4 x0 = *(const f32_4*)row, x1 = *(const f32_4*)(row+4);
        f32_4 y0 = *(const f32_4*)qq,  y1 = *(const f32_4*)(qq+4);
        float p = x0[0]*y0[0] + x0[1]*y0[1] + x0[2]*y0[2] + x0[3]*y0[3]
                + x1[0]*y1[0] + x1[1]*y1[1] + x1[2]*y1[2] + x1[3]*y1[3];
        #pragma unroll
        for (int off=32; off; off>>=1) p += __shfl_xor(p, off, 64);
        if (lane==0) a1[i] = sigmoidf_(p*SCALE);
    }
    __syncthreads();
    // a2 = clip(a1 @ weit) ; stored into a1's slot usage via a3 temp path
    __shared__ float a2[NN];
    if (t < NN){
        const float* wrow = weit + (size_t)b*NE;
        float s = 0.f;
        #pragma unroll
        for (int i=0;i<NN;i++) s = fmaf(a1[i], wrow[i*NN + t], s);
        a2[t] = fminf(fmaxf(s, 0.f), 1.f);
    }
    __syncthreads();
    for (int i=wv; i<NN; i+=8){
        const float* row = nfb + (size_t)i*DV + lane*8;
        const float* qq  = q1 + lane*8;
        f32_4 x0 = *(const f32_4*)row, x1 = *(const f32_4*)(row+4);
        f32_4 y0 = *(const f32_4*)qq,  y1 = *(const f32_4*)(qq+4);
        float p = x0[0]*y0[0] + x0[1]*y0[1] + x0[2]*y0[2] + x0[3]*y0[3]
                + x1[0]*y1[0] + x1[1]*y1[1] + x1[2]*y1[2] + x1[3]*y1[3];
        #pragma unroll
        for (int off=32; off; off>>=1) p += __shfl_xor(p, off, 64);
        if (lane==0) a3[i] = a2[i]*sigmoidf_(p*SCALE);
    }
    __syncthreads();
    if (t==0){
        float s = 0.f;
        for (int i=0;i<NN;i++) s += a3[i];
        denom = 1.f/(s + 1e-8f);
    }
    __syncthreads();
    if (t < NN) a3[t] *= denom;
    __syncthreads();

    // pooled + gate by q0: thread t owns dim t (512 dims)
    {
        float p = 0.f;
        #pragma unroll 4
        for (int i=0;i<NN;i++) p = fmaf(a3[i], nfb[(size_t)i*DV + t], p);
        xsh[t] = p * q0[t];
    }
    __syncthreads();

    // GEMV1: o = relu(x @ Wq + bq), col t
    {
        float acc = bq[t];
        #pragma unroll 8
        for (int k=0;k<DV;k++) acc = fmaf(xsh[k], Wq[(size_t)k*DV + t], acc);
        osh[t] = reluf_(acc);
    }
    __syncthreads();

    // GEMV2: h = relu(o @ Wc1 + bc1), cols 0..255
    if (t < HH){
        float acc = bc1[t];
        #pragma unroll 8
        for (int k=0;k<DV;k++) acc = fmaf(osh[k], Wc1[(size_t)k*HH + t], acc);
        hsh[t] = reluf_(acc);
    }
    __syncthreads();

    // GEMV3: out = h @ Wc2 + bc2, cols 0..27
    if (t < NCC){
        float acc = bc2[t];
        #pragma unroll 8
        for (int k=0;k<HH;k++) acc = fmaf(hsh[k], Wc2[(size_t)k*NCC + t], acc);
        out[(size_t)b*NCC + t] = acc;
    }
}

// ---------------------------------------------------------------------------
extern "C" void kernel_launch(void* const* d_in, const int* in_sizes, int n_in,
                              void* d_out, int out_size, void* d_ws, size_t ws_size,
                              hipStream_t stream)
{
    const float* node_feats = (const float*)d_in[0];
    const float* edge_feats = (const float*)d_in[1];
    const float* W_n1 = (const float*)d_in[2];
    const float* b_n1 = (const float*)d_in[3];
    const float* W_n2 = (const float*)d_in[4];
    const float* b_n2 = (const float*)d_in[5];
    const float* W_e1 = (const float*)d_in[6];
    const float* b_e1 = (const float*)d_in[7];
    const float* W_e2 = (const float*)d_in[8];
    const float* b_e2 = (const float*)d_in[9];
    const float* W_q  = (const float*)d_in[10];
    const float* b_q  = (const float*)d_in[11];
    const float* W_c1 = (const float*)d_in[12];
    const float* b_c1 = (const float*)d_in[13];
    const float* W_c2 = (const float*)d_in[14];
    const float* b_c2 = (const float*)d_in[15];
    const float* word_emb = (const float*)d_in[16];
    const int* program_inputs = (const int*)d_in[18];

    // workspace layout (all chunks 256B-aligned)
    char* ws = (char*)d_ws;
    float* qws  = (float*)ws; ws += (size_t)BB*4*DV*4;        // 1 MB
    float* ve   = (float*)ws; ws += (size_t)BB*HH*4;          // 128 KB
    float* se   = (float*)ws; ws += 512;
    __bf16* Pn1h = (__bf16*)ws; ws += (size_t)DF*HH*2;        // 256 KB
    __bf16* Pn1l = (__bf16*)ws; ws += (size_t)DF*HH*2;
    __bf16* Pn2h = (__bf16*)ws; ws += (size_t)HH*DV*2;
    __bf16* Pn2l = (__bf16*)ws; ws += (size_t)HH*DV*2;
    __bf16* Peh  = (__bf16*)ws; ws += (size_t)DE*HH*2;        // 128 KB
    float* nf   = (float*)ws; ws += (size_t)BB*NN*DV*4;       // 9 MB
    float* weit = (float*)ws; ws += (size_t)BB*NE*4;          // 648 KB

    k_setup<<<288, 256, 0, stream>>>(W_n1, W_n2, W_e1,
                                     word_emb, program_inputs, W_e2, b_e2,
                                     Pn1h, Pn1l, Pn2h, Pn2l, Peh, qws, ve, se);
    k_main<<<EBLOCKS + NODE_PAIRS, 512, 0, stream>>>(
        edge_feats, Peh, b_e1, ve, se, weit,
        node_feats, Pn1h, Pn1l, b_n1, Pn2h, Pn2l, b_n2, nf);
    k_attnhead<<<BB, 512, 0, stream>>>(nf, qws, weit,
                                       W_q, b_q, W_c1, b_c1, W_c2, b_c2,
                                       (float*)d_out);
}